// Round 9
// baseline (419.314 us; speedup 1.0000x reference)
//
#include <hip/hip_runtime.h>
#include <math.h>

// ---------------------------------------------------------------------------
// FNO-GNO round 9: fuse the x forward DFT into the spectral kernel.
//  Each spec block uses ONE kxi for all its 64 modes -> block-uniform twiddle;
//  the block computes its Ft rows from F1 in registers (16 float2 acc/thread,
//  sum order over x identical to r8's k_fwd_x => bitwise-identical output).
//  F1 is 4 MB (L2-resident), so the 8x re-read hides under spec's 11 us/layer
//  spec_w HBM stream. Removes 4 dispatches + the Ft buffer round trip.
//  All other kernels byte-identical to round 8 (passing, absmax 2.44e-4).
//  Dispatches 17 -> 13.
// ---------------------------------------------------------------------------

#define ECAP 131072

typedef _Float16 f16x8 __attribute__((ext_vector_type(8)));
typedef float f32x4 __attribute__((ext_vector_type(4)));

__device__ __forceinline__ float gelu_f(float x) {
    float t = fabsf(x) * 0.7071067811865475f;
    float k = __builtin_amdgcn_rcpf(1.0f + 0.3275911f * t);
    float e = __expf(-t * t);
    float y = k*(0.254829592f + k*(-0.284496736f + k*(1.421413741f +
              k*(-1.453152027f + k*1.061405429f))));
    float erfv = 1.0f - y * e;
    return 0.5f * x * (1.0f + copysignf(erfv, x));
}

// ---------------- prep (weights) + GNO edge build, fused --------------------
__global__ __launch_bounds__(256) void k_prep(const float* __restrict__ w2,
                                              const float* __restrict__ w3,
                                              const float* __restrict__ w1,
                                              const float* __restrict__ b1,
                                              const float* __restrict__ lw2,
                                              const float* __restrict__ skw,
                                              const float* __restrict__ out_p,
                                              _Float16* __restrict__ w2T,
                                              _Float16* __restrict__ w3T,
                                              _Float16* __restrict__ w1p,
                                              _Float16* __restrict__ l2hi,
                                              _Float16* __restrict__ l2lo,
                                              _Float16* __restrict__ skwH,
                                              _Float16* __restrict__ skwL,
                                              int* __restrict__ counter,
                                              int* __restrict__ baseG,
                                              int* __restrict__ cntG,
                                              int* __restrict__ eFlat,
                                              float* __restrict__ eAgg)
{
    if (blockIdx.x >= 720) {
        int n = (blockIdx.x - 720)*256 + threadIdx.x;
        const float hg = 1.0f/31.0f;
        const float r2 = (float)(0.033*0.033);
        float px = out_p[n*3+0], py = out_p[n*3+1], pz = out_p[n*3+2];
        int ix = (int)rintf(px*31.f), iy = (int)rintf(py*31.f), iz = (int)rintf(pz*31.f);
        unsigned msk = 0; int cnt = 0;
        for (int j = 0; j < 27; ++j) {
            int dx = j/9 - 1, dy = (j/3)%3 - 1, dz = j%3 - 1;
            int cx = ix+dx, cy = iy+dy, cz = iz+dz;
            bool inb = (cx>=0)&&(cx<32)&&(cy>=0)&&(cy<32)&&(cz>=0)&&(cz<32);
            int qx = min(max(cx,0),31), qy = min(max(cy,0),31), qz = min(max(cz,0),31);
            float yx = qx*hg, yy = qy*hg, yz = qz*hg;
            float d2 = (px-yx)*(px-yx) + (py-yy)*(py-yy) + (pz-yz)*(pz-yz);
            if (inb && d2 <= r2) { msk |= 1u<<j; cnt++; }
        }
        int base = atomicAdd(counter, cnt);
        baseG[n] = base; cntG[n] = cnt;
        int k = 0;
        for (int j = 0; j < 27; ++j) if (msk & (1u<<j)) {
            int dx = j/9 - 1, dy = (j/3)%3 - 1, dz = j%3 - 1;
            int cx = ix+dx, cy = iy+dy, cz = iz+dz;
            int e = base + k;
            eFlat[e] = (cx*32 + cy)*32 + cz;
            eAgg[e*6+0] = cx*hg; eAgg[e*6+1] = cy*hg; eAgg[e*6+2] = cz*hg;
            eAgg[e*6+3] = px;    eAgg[e*6+4] = py;    eAgg[e*6+5] = pz;
            ++k;
        }
        return;
    }
    int idx = blockIdx.x*256 + threadIdx.x;
    if (idx < 131072) {
        int k = idx >> 8, n = idx & 255;
        w2T[n*512 + k] = (_Float16)w2[idx];
    } else if (idx < 147456) {
        int j = idx - 131072;
        int k = j >> 6, o = j & 63;
        w3T[o*256 + k] = (_Float16)w3[j];
    } else if (idx < 151552) {
        int j = idx - 147456;
        int k = j >> 3, d = j & 7;
        float v = d < 6 ? w1[d*512 + k] : (d == 6 ? b1[k] : 0.0f);
        w1p[k*8 + d] = (_Float16)v;
    } else if (idx < 167936) {
        int j = idx - 151552;
        int o = j >> 8, k = j & 255;
        float v = lw2[k*64 + o];
        _Float16 hi = (_Float16)v;
        l2hi[j] = hi;
        l2lo[j] = (_Float16)(v - (float)hi);
    } else if (idx < 184320) {
        int j = idx - 167936;
        int l = j >> 12, r = j & 4095;
        int co = r >> 6, ci = r & 63;
        float v = skw[l*4096 + ci*64 + co];
        _Float16 hi = (_Float16)v;
        skwH[j] = hi;
        skwL[j] = (_Float16)(v - (float)hi);
    }
}

// ---------------- lifting via split-fp16 MFMA (unchanged) ------------------
__global__ __launch_bounds__(256) void k_lift(
    const float* __restrict__ f, const float* __restrict__ in_p,
    const float* __restrict__ w1, const float* __restrict__ b1,
    const _Float16* __restrict__ l2hi,
    const _Float16* __restrict__ l2lo,
    const float* __restrict__ b2,
    float* __restrict__ h)
{
    __shared__ __align__(16) _Float16 h1hi[64*264];
    __shared__ __align__(16) _Float16 h1lo[64*264];
    __shared__ float w1s[6*256];
    __shared__ float b1s[256];
    float* oT = (float*)h1hi;
    int t = threadIdx.x;
    for (int i = t; i < 1536; i += 256) w1s[i] = w1[i];
    b1s[t] = b1[t];
    int p0 = blockIdx.x * 64;
    int pt = t >> 2, jq = t & 3;
    int p = p0 + pt;
    float x0 = f[p*3+0], x1 = f[p*3+1], x2 = f[p*3+2];
    float x3 = in_p[p*3+0], x4 = in_p[p*3+1], x5 = in_p[p*3+2];
    __syncthreads();
    for (int r = 0; r < 8; ++r) {
        int j0 = jq*64 + r*8;
        f16x8 vh, vl;
        #pragma unroll
        for (int jj = 0; jj < 8; ++jj) {
            int j = j0 + jj;
            float a = b1s[j] + x0*w1s[j] + x1*w1s[256+j] + x2*w1s[512+j]
                    + x3*w1s[768+j] + x4*w1s[1024+j] + x5*w1s[1280+j];
            float g = gelu_f(a);
            _Float16 hi = (_Float16)g;
            vh[jj] = hi;
            vl[jj] = (_Float16)(g - (float)hi);
        }
        *(f16x8*)&h1hi[pt*264 + j0] = vh;
        *(f16x8*)&h1lo[pt*264 + j0] = vl;
    }
    __syncthreads();
    int w = t >> 6, lane = t & 63, l15 = lane & 15, g = lane >> 4;
    f32x4 acc[4];
    #pragma unroll
    for (int nt = 0; nt < 4; ++nt) {
        float bb = b2[nt*16 + l15];
        acc[nt] = (f32x4){bb, bb, bb, bb};
    }
    for (int kk = 0; kk < 8; ++kk) {
        f16x8 ah = *(const f16x8*)&h1hi[(w*16+l15)*264 + kk*32 + g*8];
        f16x8 al = *(const f16x8*)&h1lo[(w*16+l15)*264 + kk*32 + g*8];
        #pragma unroll
        for (int nt = 0; nt < 4; ++nt) {
            f16x8 bh = *(const f16x8*)&l2hi[(nt*16+l15)*256 + kk*32 + g*8];
            f16x8 bl = *(const f16x8*)&l2lo[(nt*16+l15)*256 + kk*32 + g*8];
            acc[nt] = __builtin_amdgcn_mfma_f32_16x16x32_f16(al, bh, acc[nt], 0, 0, 0);
            acc[nt] = __builtin_amdgcn_mfma_f32_16x16x32_f16(ah, bl, acc[nt], 0, 0, 0);
            acc[nt] = __builtin_amdgcn_mfma_f32_16x16x32_f16(ah, bh, acc[nt], 0, 0, 0);
        }
    }
    __syncthreads();
    #pragma unroll
    for (int nt = 0; nt < 4; ++nt)
        #pragma unroll
        for (int r = 0; r < 4; ++r)
            oT[(nt*16 + l15)*68 + w*16 + g*4 + r] = acc[nt][r];
    __syncthreads();
    for (int i = t; i < 4096; i += 256) {
        int c = i >> 6, ptl = i & 63;
        h[(size_t)c*32768 + p0 + ptl] = oT[c*68 + ptl];
    }
}

// ---------------- kA: fused z+y forward DFT (layer 0 only) -----------------
__global__ __launch_bounds__(256) void k_fwd_zy(const float* __restrict__ h,
                                                float2* __restrict__ F1)
{
    __shared__ float pl[8*1056];
    __shared__ float2 fz[32*73];
    __shared__ float twc[32], tws[32];
    int t = threadIdx.x;
    int x = blockIdx.x >> 3, cg = blockIdx.x & 7;
    for (int i = t; i < 8192; i += 256) {
        int c = i >> 10, yz = i & 1023;
        pl[c*1056 + (yz>>5)*33 + (yz&31)] = h[(cg*8 + c)*32768 + x*1024 + yz];
    }
    if (t < 32) { float th = (float)t*(6.283185307179586f/32.f); twc[t]=cosf(th); tws[t]=sinf(th); }
    __syncthreads();
    {
        int c = t >> 5, y = t & 31;
        float zv[32];
        #pragma unroll
        for (int z = 0; z < 32; ++z) zv[z] = pl[c*1056 + y*33 + z];
        const float inv = 1.0f/32768.0f;
        #pragma unroll
        for (int kz = 0; kz < 8; ++kz) {
            float re = 0.f, im = 0.f;
            #pragma unroll
            for (int z = 0; z < 32; ++z) {
                int ph = (kz*z)&31;
                re += zv[z]*twc[ph];
                im -= zv[z]*tws[ph];
            }
            fz[y*73 + kz*9 + c] = make_float2(re*inv, im*inv);
        }
    }
    __syncthreads();
    #pragma unroll
    for (int ko = 0; ko < 4; ++ko) {
        int idx = ko*256 + t;
        int kyi = idx >> 6, kz = (idx >> 3) & 7, c = idx & 7;
        int ky = kyi < 8 ? kyi : kyi + 16;
        float re = 0.f, im = 0.f;
        for (int y = 0; y < 32; ++y) {
            int ph = (ky*y)&31;
            float cc = twc[ph], ss = tws[ph];
            float2 a = fz[y*73 + kz*9 + c];
            re += a.x*cc + a.y*ss;
            im += a.y*cc - a.x*ss;
        }
        F1[((kyi*8 + kz)*32 + x)*64 + cg*8 + c] = make_float2(re, im);
    }
}

// ---------------- kB: spectral + fused x-DFT (0-255) | skip GEMM (256-511) --
// spec blocks: one kxi per block => block-uniform twiddle; each thread
// accumulates 16 modes (m = w*16+mm) for i = lane directly from F1 (L2),
// writes ft2, then the r6/r8 spec compute runs unchanged. Bitwise identical
// to the old separate k_fwd_x (same ascending-x sum order).
__global__ __launch_bounds__(256) void k_spec_skip(const float2* __restrict__ F1,
                                                   const float* __restrict__ spw,
                                                   const float* __restrict__ hold,
                                                   const _Float16* __restrict__ skwH,
                                                   const _Float16* __restrict__ skwL,
                                                   float2* __restrict__ Gt,
                                                   float* __restrict__ hsk,
                                                   int l)
{
    __shared__ __align__(16) char pool[36864];
    __shared__ float twc[32], tws[32];
    int t = threadIdx.x;
    if (blockIdx.x >= 256) {
        _Float16* shi = (_Float16*)pool;              // 128*72 halves
        _Float16* slo = (_Float16*)(pool + 18432);
        int pt0 = (blockIdx.x - 256) * 128;
        for (int i = t; i < 2048; i += 256) {
            int ci = i >> 5, q = i & 31;
            float4 v = *(const float4*)&hold[(size_t)ci*32768 + pt0 + q*4];
            #pragma unroll
            for (int j = 0; j < 4; ++j) {
                float fv = (&v.x)[j];
                _Float16 hi = (_Float16)fv;
                shi[(q*4+j)*72 + ci] = hi;
                slo[(q*4+j)*72 + ci] = (_Float16)(fv - (float)hi);
            }
        }
        __syncthreads();
        int w = t >> 6, lane = t & 63, l15 = lane & 15, g = lane >> 4;
        f32x4 acc[8];
        #pragma unroll
        for (int nt = 0; nt < 8; ++nt) acc[nt] = (f32x4){0.f, 0.f, 0.f, 0.f};
        #pragma unroll
        for (int kk = 0; kk < 2; ++kk) {
            f16x8 ah = *(const f16x8*)&skwH[l*4096 + (w*16+l15)*64 + kk*32 + g*8];
            f16x8 al = *(const f16x8*)&skwL[l*4096 + (w*16+l15)*64 + kk*32 + g*8];
            #pragma unroll
            for (int nt = 0; nt < 8; ++nt) {
                f16x8 bh = *(const f16x8*)&shi[(nt*16+l15)*72 + kk*32 + g*8];
                f16x8 bl = *(const f16x8*)&slo[(nt*16+l15)*72 + kk*32 + g*8];
                acc[nt] = __builtin_amdgcn_mfma_f32_16x16x32_f16(al, bh, acc[nt], 0, 0, 0);
                acc[nt] = __builtin_amdgcn_mfma_f32_16x16x32_f16(ah, bl, acc[nt], 0, 0, 0);
                acc[nt] = __builtin_amdgcn_mfma_f32_16x16x32_f16(ah, bh, acc[nt], 0, 0, 0);
            }
        }
        #pragma unroll
        for (int nt = 0; nt < 8; ++nt)
            #pragma unroll
            for (int r = 0; r < 4; ++r)
                hsk[(size_t)(w*16 + g*4 + r)*32768 + pt0 + nt*16 + l15] = acc[nt][r];
        return;
    }
    float2* ft2 = (float2*)pool;                      // 64*65 float2 = 33280 B
    int og8 = blockIdx.x >> 5, corner = (blockIdx.x >> 3) & 3, mx = blockIdx.x & 7;
    int kxi = mx + (corner >> 1)*8;
    int kyB = (corner & 1)*8;
    if (t < 32) { float th = (float)t*(6.283185307179586f/32.f); twc[t]=cosf(th); tws[t]=sinf(th); }
    __syncthreads();
    {   // fused x-DFT: thread (w,lane) accumulates 16 modes at i = lane
        int w = t >> 6, lane = t & 63;
        int kx = kxi < 8 ? kxi : kxi + 16;
        float2 acc[16];
        #pragma unroll
        for (int mm = 0; mm < 16; ++mm) acc[mm] = make_float2(0.f, 0.f);
        for (int x = 0; x < 32; ++x) {
            int ph = (kx*x) & 31;
            float cc = twc[ph], ss = tws[ph];
            #pragma unroll
            for (int mm = 0; mm < 16; ++mm) {
                int m = w*16 + mm;
                int my = m >> 3, mz = m & 7;
                float2 a = F1[(size_t)((((kyB + my)*8 + mz)*32 + x))*64 + lane];
                acc[mm].x += a.x*cc + a.y*ss;
                acc[mm].y += a.y*cc - a.x*ss;
            }
        }
        #pragma unroll
        for (int mm = 0; mm < 16; ++mm) {
            int m = w*16 + mm;
            int rho = (m >> 1) + ((m & 1) << 5);
            ft2[rho*65 + lane] = acc[mm];
        }
    }
    __syncthreads();
    int mp = t & 31, oq = t >> 5;
    int o = og8*8 + oq;
    int m0 = 2*mp;
    size_t wbase = (size_t)(l*4 + corner)*4194304 + (size_t)o*1024
                 + (size_t)mx*128 + m0*2;
    float ar0 = 0.f, ai0 = 0.f, ar1 = 0.f, ai1 = 0.f;
    for (int i8 = 0; i8 < 64; i8 += 8) {
        float4 wv[8];
        #pragma unroll
        for (int u = 0; u < 8; ++u)
            wv[u] = *(const float4*)&spw[wbase + (size_t)(i8+u)*65536];
        #pragma unroll
        for (int u = 0; u < 8; ++u) {
            float2 f0 = ft2[mp*65 + i8 + u];
            float2 f1 = ft2[(32 + mp)*65 + i8 + u];
            ar0 += f0.x*wv[u].x - f0.y*wv[u].y;
            ai0 += f0.x*wv[u].y + f0.y*wv[u].x;
            ar1 += f1.x*wv[u].z - f1.y*wv[u].w;
            ai1 += f1.x*wv[u].w + f1.y*wv[u].z;
        }
    }
    size_t gbase = (size_t)(o >> 2)*8192 + (size_t)(corner*8 + mx)*256 + (o & 3);
    Gt[gbase + (size_t)m0*4]       = make_float2(ar0, ai0);
    Gt[gbase + (size_t)(m0+1)*4]   = make_float2(ar1, ai1);
}

// ---------------- kC: inv-x/y/z + skip-add + gelu + NEXT-LAYER z+y DFT -----
__global__ __launch_bounds__(512) void k_inv_zy(const float2* __restrict__ Gt,
                                                const float* __restrict__ hsk,
                                                const float* __restrict__ skb,
                                                float* __restrict__ hnew,
                                                float* __restrict__ latent,
                                                float2* __restrict__ F1,
                                                int l, int do_zy)
{
    __shared__ __align__(16) char pool[58368];
    __shared__ float twc[32], tws[32];
    float2* s1 = (float2*)pool;
    float2* s2 = (float2*)(pool + 8192);
    float*  pl = (float*)(pool + 24576);
    float2* fz = (float2*)pool;

    int t = threadIdx.x;
    int x = blockIdx.x >> 3, cg = blockIdx.x & 7;
    if (t < 32) { float th = (float)t*(6.283185307179586f/32.f); twc[t]=cosf(th); tws[t]=sinf(th); }
    __syncthreads();
    #pragma unroll
    for (int ko = 0; ko < 2; ++ko) {
        int idx = ko*512 + t;
        int kyi = idx >> 6, kz = (idx >> 3) & 7, o = idx & 7;
        int cy = kyi >> 3, my = kyi & 7;
        const float2* gb = Gt + (size_t)(cg*2 + (o>>2))*8192 + my*32 + kz*4 + (o&3);
        float re = 0.f, im = 0.f;
        #pragma unroll
        for (int cxh = 0; cxh < 2; ++cxh) {
            int corner = cxh*2 + cy;
            #pragma unroll
            for (int mxx = 0; mxx < 8; ++mxx) {
                int kxi = cxh*8 + mxx;
                int kx = kxi < 8 ? kxi : kxi + 16;
                int ph = (kx * x) & 31;
                float cc = twc[ph], ss = tws[ph];
                float2 a = gb[(corner*8 + mxx)*256];
                re += a.x*cc - a.y*ss;
                im += a.x*ss + a.y*cc;
            }
        }
        s1[idx] = make_float2(re, im);
    }
    __syncthreads();
    #pragma unroll
    for (int ko = 0; ko < 4; ++ko) {
        int idx = ko*512 + t;
        int y = idx >> 6, kz = (idx >> 3) & 7, o = idx & 7;
        float re = 0.f, im = 0.f;
        #pragma unroll
        for (int kyi = 0; kyi < 16; ++kyi) {
            int ky = kyi < 8 ? kyi : kyi + 16;
            int ph = (ky*y) & 31;
            float cc = twc[ph], ss = tws[ph];
            float2 a = s1[kyi*64 + kz*8 + o];
            re += a.x*cc - a.y*ss;
            im += a.x*ss + a.y*cc;
        }
        s2[idx] = make_float2(re, im);
    }
    __syncthreads();
    {
        float outv[2][8];
        #pragma unroll
        for (int o = 0; o < 8; ++o) {
            float bb = skb[l*64 + cg*8 + o];
            float2 hv = *(const float2*)&hsk[(size_t)(cg*8+o)*32768 + x*1024 + t*2];
            outv[0][o] = bb + hv.x;
            outv[1][o] = bb + hv.y;
        }
        #pragma unroll
        for (int pp = 0; pp < 2; ++pp) {
            int pt = t*2 + pp;
            int y = pt >> 5, z = pt & 31;
            #pragma unroll
            for (int o = 0; o < 8; ++o) {
                float s = s2[y*64 + o].x;
                #pragma unroll
                for (int kz = 1; kz < 8; ++kz) {
                    int ph = (kz*z) & 31;
                    float2 a = s2[y*64 + kz*8 + o];
                    s += 2.0f*(a.x*twc[ph] - a.y*tws[ph]);
                }
                float v = s + outv[pp][o];
                outv[pp][o] = (l < 3) ? gelu_f(v) : v;
            }
        }
        if (l < 3) {
            #pragma unroll
            for (int o = 0; o < 8; ++o) {
                int pt = t*2;
                int y = pt >> 5, z = pt & 31;
                pl[o*1056 + y*33 + z]     = outv[0][o];
                pl[o*1056 + y*33 + z + 1] = outv[1][o];
                *(float2*)&hnew[(size_t)(cg*8+o)*32768 + x*1024 + pt] =
                    make_float2(outv[0][o], outv[1][o]);
            }
        } else {
            #pragma unroll
            for (int pp = 0; pp < 2; ++pp) {
                int pt = t*2 + pp;
                float4 w0 = make_float4(outv[pp][0], outv[pp][1], outv[pp][2], outv[pp][3]);
                float4 w1 = make_float4(outv[pp][4], outv[pp][5], outv[pp][6], outv[pp][7]);
                *(float4*)&latent[(size_t)(x*1024 + pt)*64 + cg*8]     = w0;
                *(float4*)&latent[(size_t)(x*1024 + pt)*64 + cg*8 + 4] = w1;
            }
        }
    }
    if (!do_zy) return;
    __syncthreads();
    {
        int c = t >> 6, y = t & 31, sub = (t >> 5) & 1;
        float zv[32];
        #pragma unroll
        for (int z = 0; z < 32; ++z) zv[z] = pl[c*1056 + y*33 + z];
        const float inv = 1.0f/32768.0f;
        #pragma unroll
        for (int kq = 0; kq < 4; ++kq) {
            int kz = sub*4 + kq;
            float re = 0.f, im = 0.f;
            #pragma unroll
            for (int z = 0; z < 32; ++z) {
                int ph = (kz*z)&31;
                re += zv[z]*twc[ph];
                im -= zv[z]*tws[ph];
            }
            fz[y*73 + kz*9 + c] = make_float2(re*inv, im*inv);
        }
    }
    __syncthreads();
    #pragma unroll
    for (int ko = 0; ko < 2; ++ko) {
        int idx = ko*512 + t;
        int kyi = idx >> 6, kz = (idx >> 3) & 7, c = idx & 7;
        int ky = kyi < 8 ? kyi : kyi + 16;
        float re = 0.f, im = 0.f;
        for (int y = 0; y < 32; ++y) {
            int ph = (ky*y)&31;
            float cc = twc[ph], ss = tws[ph];
            float2 a = fz[y*73 + kz*9 + c];
            re += a.x*cc + a.y*ss;
            im += a.y*cc - a.x*ss;
        }
        F1[((kyi*8 + kz)*32 + x)*64 + cg*8 + c] = make_float2(re, im);
    }
}

// ---------------- GNO stage 2: dense 64-edge MLP tiles (unchanged) ---------
__global__ __launch_bounds__(256, 2) void k_gno_mlp(
    const int* __restrict__ counter,
    const int* __restrict__ eFlat,
    const float* __restrict__ eAgg,
    const _Float16* __restrict__ w1p,
    const _Float16* __restrict__ w2T,
    const float* __restrict__ b2,
    const _Float16* __restrict__ w3T,
    const float* __restrict__ b3,
    const float* __restrict__ latent,
    float* __restrict__ kv)
{
    __shared__ __align__(16) _Float16 h1pool[64*520];
    __shared__ __align__(16) _Float16 w1s[512*8];
    __shared__ float aggs[64][6];
    __shared__ int   flatS[64];
    _Float16* h2h = h1pool;

    int t = threadIdx.x;
    int E = counter[0]; if (E > ECAP) E = ECAP;
    int s = blockIdx.x * 64;
    if (s >= E) return;
    int ne = min(64, E - s);

    for (int i = t; i < 512; i += 256)
        ((int4*)w1s)[i] = ((const int4*)w1p)[i];
    for (int i = t; i < 384; i += 256)
        aggs[i/6][i - (i/6)*6] = (i < ne*6) ? eAgg[(size_t)s*6 + i] : 0.0f;
    if (t < 64) flatS[t] = (t < ne) ? eFlat[s + t] : 0;
    __syncthreads();

    int e = t & 63;
    int w = t >> 6;
    {
        float a0 = aggs[e][0], a1 = aggs[e][1], a2 = aggs[e][2];
        float a3 = aggs[e][3], a4 = aggs[e][4], a5 = aggs[e][5];
        int xk = (e >> 3) & 7;
        #pragma unroll
        for (int ci = 0; ci < 16; ++ci) {
            int c = w*16 + ci;
            f16x8 v;
            #pragma unroll
            for (int jj = 0; jj < 8; ++jj) {
                int k = c*8 + jj;
                f16x8 wv = *(const f16x8*)&w1s[k*8];
                float pre = (float)wv[6]
                    + a0*(float)wv[0] + a1*(float)wv[1] + a2*(float)wv[2]
                    + a3*(float)wv[3] + a4*(float)wv[4] + a5*(float)wv[5];
                v[jj] = (_Float16)gelu_f(pre);
            }
            *(f16x8*)&h1pool[e*520 + ((c ^ xk)*8)] = v;
        }
    }
    __syncthreads();

    int lane = t & 63;
    int l15 = lane & 15, g = lane >> 4;

    f32x4 acc2[4][4];
    #pragma unroll
    for (int nt = 0; nt < 4; ++nt) {
        float bb = b2[w*64 + nt*16 + l15];
        #pragma unroll
        for (int mt = 0; mt < 4; ++mt) acc2[mt][nt] = (f32x4){bb, bb, bb, bb};
    }
    #pragma unroll 4
    for (int kk = 0; kk < 16; ++kk) {
        f16x8 af[4];
        #pragma unroll
        for (int mt = 0; mt < 4; ++mt) {
            int ee = mt*16 + l15;
            af[mt] = *(const f16x8*)&h1pool[ee*520 + (((kk*4 + g) ^ ((ee>>3)&7))*8)];
        }
        #pragma unroll
        for (int nt = 0; nt < 4; ++nt) {
            f16x8 bf = *(const f16x8*)&w2T[(size_t)(w*64 + nt*16 + l15)*512 + kk*32 + g*8];
            #pragma unroll
            for (int mt = 0; mt < 4; ++mt)
                acc2[mt][nt] = __builtin_amdgcn_mfma_f32_16x16x32_f16(af[mt], bf, acc2[mt][nt], 0, 0, 0);
        }
    }
    __syncthreads();
    #pragma unroll
    for (int mt = 0; mt < 4; ++mt)
      #pragma unroll
      for (int nt = 0; nt < 4; ++nt) {
        int n = w*64 + nt*16 + l15;
        #pragma unroll
        for (int r = 0; r < 4; ++r) {
            int m = mt*16 + g*4 + r;
            h2h[m*264 + (((n>>3) ^ (m&7))*8) + (n&7)] = (_Float16)gelu_f(acc2[mt][nt][r]);
        }
      }
    __syncthreads();

    int o = w*16 + l15;
    f32x4 acc3[4];
    { float bb = b3[o];
      #pragma unroll
      for (int mt = 0; mt < 4; ++mt) acc3[mt] = (f32x4){bb, bb, bb, bb}; }
    #pragma unroll 2
    for (int kk2 = 0; kk2 < 8; ++kk2) {
        f16x8 bf = *(const f16x8*)&w3T[(size_t)o*256 + kk2*32 + g*8];
        #pragma unroll
        for (int mt = 0; mt < 4; ++mt) {
            int ee = mt*16 + l15;
            f16x8 af = *(const f16x8*)&h2h[ee*264 + (((kk2*4 + g) ^ (ee&7))*8)];
            acc3[mt] = __builtin_amdgcn_mfma_f32_16x16x32_f16(af, bf, acc3[mt], 0, 0, 0);
        }
    }

    #pragma unroll
    for (int mt = 0; mt < 4; ++mt) {
        #pragma unroll
        for (int r = 0; r < 4; ++r) {
            int ee = mt*16 + g*4 + r;
            if (ee < ne) {
                float fy = latent[(size_t)flatS[ee]*64 + o];
                kv[(size_t)(s + ee)*64 + o] = acc3[mt][r] * fy;
            }
        }
    }
}

// ---------------- projection + kv gather (unchanged) -----------------------
__global__ __launch_bounds__(256) void k_project(const int* __restrict__ baseG,
                                                 const int* __restrict__ cntG,
                                                 const float* __restrict__ kv,
                                                 const float* __restrict__ pw1,
                                                 const float* __restrict__ pb1,
                                                 const float* __restrict__ pw2,
                                                 const float* __restrict__ pb2,
                                                 float* __restrict__ outp)
{
    __shared__ float w1s[64*260];
    __shared__ float xT[64*68];
    __shared__ float w2s[256];
    __shared__ float b1s[256];
    __shared__ float red[64*4];
    int t = threadIdx.x;
    int p0 = blockIdx.x * 64;
    for (int i = t; i < 16384; i += 256) {
        int k = i >> 8, o = i & 255;
        w1s[k*260 + o] = pw1[i];
    }
    w2s[t] = pw2[t];
    b1s[t] = pb1[t];
    for (int i = t; i < 4096; i += 256) {
        int ptl = i >> 6, c = i & 63;
        int p = p0 + ptl;
        int base = baseG[p], cnt = cntG[p];
        float acc = 0.f;
        for (int j = 0; j < cnt; ++j) acc += kv[(size_t)(base + j)*64 + c];
        xT[c*68 + ptl] = acc / fmaxf((float)cnt, 1.0f);
    }
    __syncthreads();
    int pr = t & 15, oc0 = t >> 4;
    float psum[4] = {0.f, 0.f, 0.f, 0.f};
    for (int it = 0; it < 4; ++it) {
        int oc = it*16 + oc0;
        float a[4][4];
        #pragma unroll
        for (int pp = 0; pp < 4; ++pp)
            #pragma unroll
            for (int q = 0; q < 4; ++q) a[pp][q] = b1s[oc*4 + q];
        for (int i = 0; i < 64; ++i) {
            float4 xv = *(const float4*)&xT[i*68 + pr*4];
            float4 wv = *(const float4*)&w1s[i*260 + oc*4];
            #pragma unroll
            for (int q = 0; q < 4; ++q) {
                float wq = (&wv.x)[q];
                a[0][q] += xv.x*wq; a[1][q] += xv.y*wq;
                a[2][q] += xv.z*wq; a[3][q] += xv.w*wq;
            }
        }
        #pragma unroll
        for (int pp = 0; pp < 4; ++pp) {
            float s = 0.f;
            #pragma unroll
            for (int q = 0; q < 4; ++q) s += gelu_f(a[pp][q]) * w2s[oc*4 + q];
            psum[pp] += s;
        }
    }
    #pragma unroll
    for (int pp = 0; pp < 4; ++pp) {
        psum[pp] += __shfl_xor(psum[pp], 16, 64);
        psum[pp] += __shfl_xor(psum[pp], 32, 64);
    }
    int lane = t & 63, w = t >> 6;
    if (lane < 16) {
        #pragma unroll
        for (int pp = 0; pp < 4; ++pp) red[(lane*4 + pp)*4 + w] = psum[pp];
    }
    __syncthreads();
    if (t < 64)
        outp[p0 + t] = red[t*4+0] + red[t*4+1] + red[t*4+2] + red[t*4+3] + pb2[0];
}

// ---------------------------------------------------------------------------
extern "C" void kernel_launch(void* const* d_in, const int* in_sizes, int n_in,
                              void* d_out, int out_size, void* d_ws, size_t ws_size,
                              hipStream_t stream)
{
    const float* in_p = (const float*)d_in[0];
    const float* outp = (const float*)d_in[1];
    const float* f    = (const float*)d_in[2];
    const float* lw1  = (const float*)d_in[3];
    const float* lb1  = (const float*)d_in[4];
    const float* lw2  = (const float*)d_in[5];
    const float* lb2  = (const float*)d_in[6];
    const float* spw  = (const float*)d_in[7];
    const float* skw  = (const float*)d_in[8];
    const float* skb  = (const float*)d_in[9];
    const float* gw1  = (const float*)d_in[10];
    const float* gb1  = (const float*)d_in[11];
    const float* gw2  = (const float*)d_in[12];
    const float* gb2  = (const float*)d_in[13];
    const float* gw3  = (const float*)d_in[14];
    const float* gb3  = (const float*)d_in[15];
    const float* pw1  = (const float*)d_in[16];
    const float* pb1  = (const float*)d_in[17];
    const float* pw2  = (const float*)d_in[18];
    const float* pb2  = (const float*)d_in[19];

    float* ws   = (float*)d_ws;
    float* buf0 = ws;
    float* buf1 = ws + 2097152;
    float* SC   = ws + 4194304;
    float2* F1 = (float2*)SC;
    float2* Gt = (float2*)(SC + 786432);
    _Float16* w2T  = (_Float16*)(SC + 1048576);
    _Float16* w3T  = (_Float16*)(SC + 1114112);
    _Float16* w1p  = (_Float16*)(SC + 1122304);
    _Float16* l2hi = (_Float16*)(SC + 1124352);
    _Float16* l2lo = (_Float16*)(SC + 1132544);
    _Float16* skwH = (_Float16*)(SC + 1140736);
    _Float16* skwL = (_Float16*)(SC + 1148928);
    int*   counter = (int*)(SC + 1157120);
    int*   baseG   = (int*)(SC + 1157136);
    int*   cntG    = (int*)(SC + 1173520);
    int*   eFlat   = (int*)(SC + 1189904);
    float* eAgg    = SC + 1320976;
    float* kv      = SC + 2107408;
    float* hsk     = SC + 10496016;

    hipMemsetAsync(counter, 0, sizeof(int), stream);
    k_prep<<<784, 256, 0, stream>>>(gw2, gw3, gw1, gb1, lw2, skw, outp,
                                    w2T, w3T, w1p, l2hi, l2lo, skwH, skwL,
                                    counter, baseG, cntG, eFlat, eAgg);
    k_lift<<<512, 256, 0, stream>>>(f, in_p, lw1, lb1, l2hi, l2lo, lb2, buf0);

    k_fwd_zy<<<256, 256, 0, stream>>>(buf0, F1);
    for (int l = 0; l < 4; ++l) {
        const float* hin = (l & 1) ? buf1 : buf0;
        float* hout = (l & 1) ? buf0 : buf1;
        k_spec_skip<<<512, 256, 0, stream>>>(F1, spw, hin, skwH, skwL, Gt, hsk, l);
        k_inv_zy<<<256, 512, 0, stream>>>(Gt, hsk, skb, hout, buf0, F1,
                                          l, (l < 3) ? 1 : 0);
    }
    // latent = buf0 (point-major, written by k_inv_zy at l=3)

    k_gno_mlp<<<ECAP/64, 256, 0, stream>>>(counter, eFlat, eAgg,
                                           w1p, w2T, gb2, w3T, gb3, buf0, kv);
    k_project<<<256, 256, 0, stream>>>(baseG, cntG, kv, pw1, pb1, pw2, pb2,
                                       (float*)d_out);
}

// Round 10
// 356.851 us; speedup vs baseline: 1.1750x; 1.1750x over previous
//
#include <hip/hip_runtime.h>
#include <math.h>

// ---------------------------------------------------------------------------
// FNO-GNO round 10: revert r9's fused-x-DFT regression (redundant F1 L2 reads
// on the critical path, +62us). Back to r8 structure + one occupancy fix:
//  k_inv_zy split cg8 -> cg4: 512 blocks x 256 thr, ~29 KB LDS (2+ blocks/CU,
//  was 1), s2 rows padded (stride 33) to break 8-way bank aliasing in inv-z.
//  Identical sum orders => bitwise-identical output (absmax 2.44e-4).
// ---------------------------------------------------------------------------

#define ECAP 131072

typedef _Float16 f16x8 __attribute__((ext_vector_type(8)));
typedef float f32x4 __attribute__((ext_vector_type(4)));

__device__ __forceinline__ float gelu_f(float x) {
    float t = fabsf(x) * 0.7071067811865475f;
    float k = __builtin_amdgcn_rcpf(1.0f + 0.3275911f * t);
    float e = __expf(-t * t);
    float y = k*(0.254829592f + k*(-0.284496736f + k*(1.421413741f +
              k*(-1.453152027f + k*1.061405429f))));
    float erfv = 1.0f - y * e;
    return 0.5f * x * (1.0f + copysignf(erfv, x));
}

// ---------------- prep (weights) + GNO edge build, fused --------------------
__global__ __launch_bounds__(256) void k_prep(const float* __restrict__ w2,
                                              const float* __restrict__ w3,
                                              const float* __restrict__ w1,
                                              const float* __restrict__ b1,
                                              const float* __restrict__ lw2,
                                              const float* __restrict__ skw,
                                              const float* __restrict__ out_p,
                                              _Float16* __restrict__ w2T,
                                              _Float16* __restrict__ w3T,
                                              _Float16* __restrict__ w1p,
                                              _Float16* __restrict__ l2hi,
                                              _Float16* __restrict__ l2lo,
                                              _Float16* __restrict__ skwH,
                                              _Float16* __restrict__ skwL,
                                              int* __restrict__ counter,
                                              int* __restrict__ baseG,
                                              int* __restrict__ cntG,
                                              int* __restrict__ eFlat,
                                              float* __restrict__ eAgg)
{
    if (blockIdx.x >= 720) {
        int n = (blockIdx.x - 720)*256 + threadIdx.x;
        const float hg = 1.0f/31.0f;
        const float r2 = (float)(0.033*0.033);
        float px = out_p[n*3+0], py = out_p[n*3+1], pz = out_p[n*3+2];
        int ix = (int)rintf(px*31.f), iy = (int)rintf(py*31.f), iz = (int)rintf(pz*31.f);
        unsigned msk = 0; int cnt = 0;
        for (int j = 0; j < 27; ++j) {
            int dx = j/9 - 1, dy = (j/3)%3 - 1, dz = j%3 - 1;
            int cx = ix+dx, cy = iy+dy, cz = iz+dz;
            bool inb = (cx>=0)&&(cx<32)&&(cy>=0)&&(cy<32)&&(cz>=0)&&(cz<32);
            int qx = min(max(cx,0),31), qy = min(max(cy,0),31), qz = min(max(cz,0),31);
            float yx = qx*hg, yy = qy*hg, yz = qz*hg;
            float d2 = (px-yx)*(px-yx) + (py-yy)*(py-yy) + (pz-yz)*(pz-yz);
            if (inb && d2 <= r2) { msk |= 1u<<j; cnt++; }
        }
        int base = atomicAdd(counter, cnt);
        baseG[n] = base; cntG[n] = cnt;
        int k = 0;
        for (int j = 0; j < 27; ++j) if (msk & (1u<<j)) {
            int dx = j/9 - 1, dy = (j/3)%3 - 1, dz = j%3 - 1;
            int cx = ix+dx, cy = iy+dy, cz = iz+dz;
            int e = base + k;
            eFlat[e] = (cx*32 + cy)*32 + cz;
            eAgg[e*6+0] = cx*hg; eAgg[e*6+1] = cy*hg; eAgg[e*6+2] = cz*hg;
            eAgg[e*6+3] = px;    eAgg[e*6+4] = py;    eAgg[e*6+5] = pz;
            ++k;
        }
        return;
    }
    int idx = blockIdx.x*256 + threadIdx.x;
    if (idx < 131072) {
        int k = idx >> 8, n = idx & 255;
        w2T[n*512 + k] = (_Float16)w2[idx];
    } else if (idx < 147456) {
        int j = idx - 131072;
        int k = j >> 6, o = j & 63;
        w3T[o*256 + k] = (_Float16)w3[j];
    } else if (idx < 151552) {
        int j = idx - 147456;
        int k = j >> 3, d = j & 7;
        float v = d < 6 ? w1[d*512 + k] : (d == 6 ? b1[k] : 0.0f);
        w1p[k*8 + d] = (_Float16)v;
    } else if (idx < 167936) {
        int j = idx - 151552;
        int o = j >> 8, k = j & 255;
        float v = lw2[k*64 + o];
        _Float16 hi = (_Float16)v;
        l2hi[j] = hi;
        l2lo[j] = (_Float16)(v - (float)hi);
    } else if (idx < 184320) {
        int j = idx - 167936;
        int l = j >> 12, r = j & 4095;
        int co = r >> 6, ci = r & 63;
        float v = skw[l*4096 + ci*64 + co];
        _Float16 hi = (_Float16)v;
        skwH[j] = hi;
        skwL[j] = (_Float16)(v - (float)hi);
    }
}

// ---------------- lifting via split-fp16 MFMA (unchanged) ------------------
__global__ __launch_bounds__(256) void k_lift(
    const float* __restrict__ f, const float* __restrict__ in_p,
    const float* __restrict__ w1, const float* __restrict__ b1,
    const _Float16* __restrict__ l2hi,
    const _Float16* __restrict__ l2lo,
    const float* __restrict__ b2,
    float* __restrict__ h)
{
    __shared__ __align__(16) _Float16 h1hi[64*264];
    __shared__ __align__(16) _Float16 h1lo[64*264];
    __shared__ float w1s[6*256];
    __shared__ float b1s[256];
    float* oT = (float*)h1hi;
    int t = threadIdx.x;
    for (int i = t; i < 1536; i += 256) w1s[i] = w1[i];
    b1s[t] = b1[t];
    int p0 = blockIdx.x * 64;
    int pt = t >> 2, jq = t & 3;
    int p = p0 + pt;
    float x0 = f[p*3+0], x1 = f[p*3+1], x2 = f[p*3+2];
    float x3 = in_p[p*3+0], x4 = in_p[p*3+1], x5 = in_p[p*3+2];
    __syncthreads();
    for (int r = 0; r < 8; ++r) {
        int j0 = jq*64 + r*8;
        f16x8 vh, vl;
        #pragma unroll
        for (int jj = 0; jj < 8; ++jj) {
            int j = j0 + jj;
            float a = b1s[j] + x0*w1s[j] + x1*w1s[256+j] + x2*w1s[512+j]
                    + x3*w1s[768+j] + x4*w1s[1024+j] + x5*w1s[1280+j];
            float g = gelu_f(a);
            _Float16 hi = (_Float16)g;
            vh[jj] = hi;
            vl[jj] = (_Float16)(g - (float)hi);
        }
        *(f16x8*)&h1hi[pt*264 + j0] = vh;
        *(f16x8*)&h1lo[pt*264 + j0] = vl;
    }
    __syncthreads();
    int w = t >> 6, lane = t & 63, l15 = lane & 15, g = lane >> 4;
    f32x4 acc[4];
    #pragma unroll
    for (int nt = 0; nt < 4; ++nt) {
        float bb = b2[nt*16 + l15];
        acc[nt] = (f32x4){bb, bb, bb, bb};
    }
    for (int kk = 0; kk < 8; ++kk) {
        f16x8 ah = *(const f16x8*)&h1hi[(w*16+l15)*264 + kk*32 + g*8];
        f16x8 al = *(const f16x8*)&h1lo[(w*16+l15)*264 + kk*32 + g*8];
        #pragma unroll
        for (int nt = 0; nt < 4; ++nt) {
            f16x8 bh = *(const f16x8*)&l2hi[(nt*16+l15)*256 + kk*32 + g*8];
            f16x8 bl = *(const f16x8*)&l2lo[(nt*16+l15)*256 + kk*32 + g*8];
            acc[nt] = __builtin_amdgcn_mfma_f32_16x16x32_f16(al, bh, acc[nt], 0, 0, 0);
            acc[nt] = __builtin_amdgcn_mfma_f32_16x16x32_f16(ah, bl, acc[nt], 0, 0, 0);
            acc[nt] = __builtin_amdgcn_mfma_f32_16x16x32_f16(ah, bh, acc[nt], 0, 0, 0);
        }
    }
    __syncthreads();
    #pragma unroll
    for (int nt = 0; nt < 4; ++nt)
        #pragma unroll
        for (int r = 0; r < 4; ++r)
            oT[(nt*16 + l15)*68 + w*16 + g*4 + r] = acc[nt][r];
    __syncthreads();
    for (int i = t; i < 4096; i += 256) {
        int c = i >> 6, ptl = i & 63;
        h[(size_t)c*32768 + p0 + ptl] = oT[c*68 + ptl];
    }
}

// ---------------- kA: fused z+y forward DFT (layer 0 only) -----------------
__global__ __launch_bounds__(256) void k_fwd_zy(const float* __restrict__ h,
                                                float2* __restrict__ F1)
{
    __shared__ float pl[8*1056];
    __shared__ float2 fz[32*73];
    __shared__ float twc[32], tws[32];
    int t = threadIdx.x;
    int x = blockIdx.x >> 3, cg = blockIdx.x & 7;
    for (int i = t; i < 8192; i += 256) {
        int c = i >> 10, yz = i & 1023;
        pl[c*1056 + (yz>>5)*33 + (yz&31)] = h[(cg*8 + c)*32768 + x*1024 + yz];
    }
    if (t < 32) { float th = (float)t*(6.283185307179586f/32.f); twc[t]=cosf(th); tws[t]=sinf(th); }
    __syncthreads();
    {
        int c = t >> 5, y = t & 31;
        float zv[32];
        #pragma unroll
        for (int z = 0; z < 32; ++z) zv[z] = pl[c*1056 + y*33 + z];
        const float inv = 1.0f/32768.0f;
        #pragma unroll
        for (int kz = 0; kz < 8; ++kz) {
            float re = 0.f, im = 0.f;
            #pragma unroll
            for (int z = 0; z < 32; ++z) {
                int ph = (kz*z)&31;
                re += zv[z]*twc[ph];
                im -= zv[z]*tws[ph];
            }
            fz[y*73 + kz*9 + c] = make_float2(re*inv, im*inv);
        }
    }
    __syncthreads();
    #pragma unroll
    for (int ko = 0; ko < 4; ++ko) {
        int idx = ko*256 + t;
        int kyi = idx >> 6, kz = (idx >> 3) & 7, c = idx & 7;
        int ky = kyi < 8 ? kyi : kyi + 16;
        float re = 0.f, im = 0.f;
        for (int y = 0; y < 32; ++y) {
            int ph = (ky*y)&31;
            float cc = twc[ph], ss = tws[ph];
            float2 a = fz[y*73 + kz*9 + c];
            re += a.x*cc + a.y*ss;
            im += a.y*cc - a.x*ss;
        }
        F1[((kyi*8 + kz)*32 + x)*64 + cg*8 + c] = make_float2(re, im);
    }
}

// ---------------- kAx: x forward DFT, 256 blocks (r8) ----------------------
__global__ __launch_bounds__(256) void k_fwd_x(const float2* __restrict__ F1,
                                               float2* __restrict__ Ft)
{
    __shared__ float2 fs[32*33];
    __shared__ float twc[32], tws[32];
    int t = threadIdx.x;
    int b = blockIdx.x;
    int kyi = b >> 4, kz = (b >> 1) & 7, ih = b & 1;
    const float2* src = &F1[(size_t)((kyi*8 + kz)*32)*64 + ih*32];
    for (int i = t; i < 1024; i += 256) {
        int xx = i >> 5, il = i & 31;
        fs[xx*33 + il] = src[xx*64 + il];
    }
    if (t < 32) { float th = (float)t*(6.283185307179586f/32.f); twc[t]=cosf(th); tws[t]=sinf(th); }
    __syncthreads();
    #pragma unroll
    for (int ko = 0; ko < 2; ++ko) {
        int idx = ko*256 + t;
        int kxi = idx >> 5, il = idx & 31;
        int kx = kxi < 8 ? kxi : kxi + 16;
        float re = 0.f, im = 0.f;
        for (int xx = 0; xx < 32; ++xx) {
            int ph = (kx*xx)&31;
            float cc = twc[ph], ss = tws[ph];
            float2 a = fs[xx*33 + il];
            re += a.x*cc + a.y*ss;
            im += a.y*cc - a.x*ss;
        }
        Ft[((kxi*16 + kyi)*8 + kz)*64 + ih*32 + il] = make_float2(re, im);
    }
}

// ---------------- kB: spectral (0-255) + skip GEMM (256-511), LDS overlay --
__global__ __launch_bounds__(256) void k_spec_skip(const float2* __restrict__ Ft,
                                                   const float* __restrict__ spw,
                                                   const float* __restrict__ hold,
                                                   const _Float16* __restrict__ skwH,
                                                   const _Float16* __restrict__ skwL,
                                                   float2* __restrict__ Gt,
                                                   float* __restrict__ hsk,
                                                   int l)
{
    __shared__ __align__(16) char pool[36864];
    int t = threadIdx.x;
    if (blockIdx.x >= 256) {
        _Float16* shi = (_Float16*)pool;              // 128*72 halves
        _Float16* slo = (_Float16*)(pool + 18432);
        int pt0 = (blockIdx.x - 256) * 128;
        for (int i = t; i < 2048; i += 256) {
            int ci = i >> 5, q = i & 31;
            float4 v = *(const float4*)&hold[(size_t)ci*32768 + pt0 + q*4];
            #pragma unroll
            for (int j = 0; j < 4; ++j) {
                float fv = (&v.x)[j];
                _Float16 hi = (_Float16)fv;
                shi[(q*4+j)*72 + ci] = hi;
                slo[(q*4+j)*72 + ci] = (_Float16)(fv - (float)hi);
            }
        }
        __syncthreads();
        int w = t >> 6, lane = t & 63, l15 = lane & 15, g = lane >> 4;
        f32x4 acc[8];
        #pragma unroll
        for (int nt = 0; nt < 8; ++nt) acc[nt] = (f32x4){0.f, 0.f, 0.f, 0.f};
        #pragma unroll
        for (int kk = 0; kk < 2; ++kk) {
            f16x8 ah = *(const f16x8*)&skwH[l*4096 + (w*16+l15)*64 + kk*32 + g*8];
            f16x8 al = *(const f16x8*)&skwL[l*4096 + (w*16+l15)*64 + kk*32 + g*8];
            #pragma unroll
            for (int nt = 0; nt < 8; ++nt) {
                f16x8 bh = *(const f16x8*)&shi[(nt*16+l15)*72 + kk*32 + g*8];
                f16x8 bl = *(const f16x8*)&slo[(nt*16+l15)*72 + kk*32 + g*8];
                acc[nt] = __builtin_amdgcn_mfma_f32_16x16x32_f16(al, bh, acc[nt], 0, 0, 0);
                acc[nt] = __builtin_amdgcn_mfma_f32_16x16x32_f16(ah, bl, acc[nt], 0, 0, 0);
                acc[nt] = __builtin_amdgcn_mfma_f32_16x16x32_f16(ah, bh, acc[nt], 0, 0, 0);
            }
        }
        #pragma unroll
        for (int nt = 0; nt < 8; ++nt)
            #pragma unroll
            for (int r = 0; r < 4; ++r)
                hsk[(size_t)(w*16 + g*4 + r)*32768 + pt0 + nt*16 + l15] = acc[nt][r];
        return;
    }
    float2* ft2 = (float2*)pool;                      // 64*65 float2 = 33280 B
    int og8 = blockIdx.x >> 5, corner = (blockIdx.x >> 3) & 3, mx = blockIdx.x & 7;
    int kxi = mx + (corner >> 1)*8;
    int kyB = (corner & 1)*8;
    {
        int m = t >> 2, iq = t & 3;
        int my = m >> 3, mz = m & 7;
        int rho = (m >> 1) + ((m & 1) << 5);
        const float2* src = &Ft[(size_t)((kxi*16 + kyB + my)*8 + mz)*64];
        #pragma unroll
        for (int ii = 0; ii < 16; ++ii) {
            int i = iq*16 + ii;
            ft2[rho*65 + i] = src[i];
        }
    }
    __syncthreads();
    int mp = t & 31, oq = t >> 5;
    int o = og8*8 + oq;
    int m0 = 2*mp;
    size_t wbase = (size_t)(l*4 + corner)*4194304 + (size_t)o*1024
                 + (size_t)mx*128 + m0*2;
    float ar0 = 0.f, ai0 = 0.f, ar1 = 0.f, ai1 = 0.f;
    for (int i8 = 0; i8 < 64; i8 += 8) {
        float4 wv[8];
        #pragma unroll
        for (int u = 0; u < 8; ++u)
            wv[u] = *(const float4*)&spw[wbase + (size_t)(i8+u)*65536];
        #pragma unroll
        for (int u = 0; u < 8; ++u) {
            float2 f0 = ft2[mp*65 + i8 + u];
            float2 f1 = ft2[(32 + mp)*65 + i8 + u];
            ar0 += f0.x*wv[u].x - f0.y*wv[u].y;
            ai0 += f0.x*wv[u].y + f0.y*wv[u].x;
            ar1 += f1.x*wv[u].z - f1.y*wv[u].w;
            ai1 += f1.x*wv[u].w + f1.y*wv[u].z;
        }
    }
    size_t gbase = (size_t)(o >> 2)*8192 + (size_t)(corner*8 + mx)*256 + (o & 3);
    Gt[gbase + (size_t)m0*4]       = make_float2(ar0, ai0);
    Gt[gbase + (size_t)(m0+1)*4]   = make_float2(ar1, ai1);
}

// ---------------- kC: inv-x/y/z + skip-add + gelu + next-layer z+y DFT -----
// grid 512 = (x 32) x (cg4 16); 256 threads; ~29 KB LDS => 2+ blocks/CU.
// Same sum orders as r8 => bitwise-identical outputs.
__global__ __launch_bounds__(256) void k_inv_zy(const float2* __restrict__ Gt,
                                                const float* __restrict__ hsk,
                                                const float* __restrict__ skb,
                                                float* __restrict__ hnew,
                                                float* __restrict__ latent,
                                                float2* __restrict__ F1,
                                                int l, int do_zy)
{
    __shared__ __align__(16) char pool[29568];
    __shared__ float twc[32], tws[32];
    float2* s1 = (float2*)pool;                  // [kyi16][kz8][o4]       4096 B
    float2* s2 = (float2*)(pool + 4096);         // [y32][33-pad rows]     8448 B
    float*  pl = (float*)(pool + 12544);         // [c4][y32][z33]        16896 B
    float2* fz = (float2*)pool;                  // [y32][33] aliases s1/s2 (8448 B)

    int t = threadIdx.x;
    int x = blockIdx.x >> 4, cg = blockIdx.x & 15;
    if (t < 32) { float th = (float)t*(6.283185307179586f/32.f); twc[t]=cosf(th); tws[t]=sinf(th); }
    __syncthreads();
    // phase A: inv-x (direct Gt reads from L2)
    #pragma unroll
    for (int ko = 0; ko < 2; ++ko) {
        int idx = ko*256 + t;                    // (kyi*8+kz)*4 + o
        int kyi = idx >> 5, kz = (idx >> 2) & 7, o = idx & 3;
        int cy = kyi >> 3, my = kyi & 7;
        const float2* gb = Gt + (size_t)cg*8192 + my*32 + kz*4 + o;
        float re = 0.f, im = 0.f;
        #pragma unroll
        for (int cxh = 0; cxh < 2; ++cxh) {
            int corner = cxh*2 + cy;
            #pragma unroll
            for (int mxx = 0; mxx < 8; ++mxx) {
                int kxi = cxh*8 + mxx;
                int kx = kxi < 8 ? kxi : kxi + 16;
                int ph = (kx * x) & 31;
                float cc = twc[ph], ss = tws[ph];
                float2 a = gb[(corner*8 + mxx)*256];
                re += a.x*cc - a.y*ss;
                im += a.x*ss + a.y*cc;
            }
        }
        s1[idx] = make_float2(re, im);
    }
    __syncthreads();
    // phase B: inv-y (s2 rows padded: stride 33)
    #pragma unroll
    for (int ko = 0; ko < 4; ++ko) {
        int idx = ko*256 + t;                    // (y*8+kz)*4 + o
        int y = idx >> 5, rem = idx & 31;        // rem = kz*4+o
        int kz = rem >> 2, o = rem & 3;
        float re = 0.f, im = 0.f;
        #pragma unroll
        for (int kyi = 0; kyi < 16; ++kyi) {
            int ky = kyi < 8 ? kyi : kyi + 16;
            int ph = (ky*y) & 31;
            float cc = twc[ph], ss = tws[ph];
            float2 a = s1[kyi*32 + kz*4 + o];
            re += a.x*cc - a.y*ss;
            im += a.x*ss + a.y*cc;
        }
        s2[y*33 + rem] = make_float2(re, im);
    }
    __syncthreads();
    // phase C: inv-z + skip-add + gelu; thread owns 4 points x 4 channels
    {
        float outv[4][4];
        #pragma unroll
        for (int o = 0; o < 4; ++o) {
            float bb = skb[l*64 + cg*4 + o];
            float4 hv = *(const float4*)&hsk[(size_t)(cg*4+o)*32768 + x*1024 + t*4];
            outv[0][o] = bb + hv.x; outv[1][o] = bb + hv.y;
            outv[2][o] = bb + hv.z; outv[3][o] = bb + hv.w;
        }
        #pragma unroll
        for (int pp = 0; pp < 4; ++pp) {
            int pt = t*4 + pp;
            int y = pt >> 5, z = pt & 31;
            #pragma unroll
            for (int o = 0; o < 4; ++o) {
                float s = s2[y*33 + o].x;        // kz=0 (imag discarded)
                #pragma unroll
                for (int kz = 1; kz < 8; ++kz) {
                    int ph = (kz*z) & 31;
                    float2 a = s2[y*33 + kz*4 + o];
                    s += 2.0f*(a.x*twc[ph] - a.y*tws[ph]);
                }
                float v = s + outv[pp][o];
                outv[pp][o] = (l < 3) ? gelu_f(v) : v;
            }
        }
        if (l < 3) {
            int pt = t*4;
            int y = pt >> 5, z = pt & 31;       // 4 consecutive z, same y
            #pragma unroll
            for (int o = 0; o < 4; ++o) {
                pl[o*1056 + y*33 + z + 0] = outv[0][o];
                pl[o*1056 + y*33 + z + 1] = outv[1][o];
                pl[o*1056 + y*33 + z + 2] = outv[2][o];
                pl[o*1056 + y*33 + z + 3] = outv[3][o];
                *(float4*)&hnew[(size_t)(cg*4+o)*32768 + x*1024 + pt] =
                    make_float4(outv[0][o], outv[1][o], outv[2][o], outv[3][o]);
            }
        } else {
            #pragma unroll
            for (int pp = 0; pp < 4; ++pp) {
                int pt = t*4 + pp;
                *(float4*)&latent[(size_t)(x*1024 + pt)*64 + cg*4] =
                    make_float4(outv[pp][0], outv[pp][1], outv[pp][2], outv[pp][3]);
            }
        }
    }
    if (!do_zy) return;
    __syncthreads();
    // fused next-layer z-stage: thread (c = t>>6, y = (t>>1)&31, sub = t&1)
    {
        int c = t >> 6, y = (t >> 1) & 31, sub = t & 1;
        float zv[32];
        #pragma unroll
        for (int z = 0; z < 32; ++z) zv[z] = pl[c*1056 + y*33 + z];
        const float inv = 1.0f/32768.0f;
        #pragma unroll
        for (int kq = 0; kq < 4; ++kq) {
            int kz = sub*4 + kq;
            float re = 0.f, im = 0.f;
            #pragma unroll
            for (int z = 0; z < 32; ++z) {
                int ph = (kz*z)&31;
                re += zv[z]*twc[ph];
                im -= zv[z]*tws[ph];
            }
            fz[y*33 + kz*4 + c] = make_float2(re*inv, im*inv);
        }
    }
    __syncthreads();
    // fused next-layer y-stage -> F1
    #pragma unroll
    for (int ko = 0; ko < 2; ++ko) {
        int idx = ko*256 + t;                    // kyi*32 + kz*4 + c
        int kyi = idx >> 5, rem = idx & 31;
        int kz = rem >> 2, c = rem & 3;
        int ky = kyi < 8 ? kyi : kyi + 16;
        float re = 0.f, im = 0.f;
        for (int y = 0; y < 32; ++y) {
            int ph = (ky*y)&31;
            float cc = twc[ph], ss = tws[ph];
            float2 a = fz[y*33 + kz*4 + c];
            re += a.x*cc + a.y*ss;
            im += a.y*cc - a.x*ss;
        }
        F1[((kyi*8 + kz)*32 + x)*64 + cg*4 + c] = make_float2(re, im);
    }
}

// ---------------- GNO stage 2: dense 64-edge MLP tiles (unchanged) ---------
__global__ __launch_bounds__(256, 2) void k_gno_mlp(
    const int* __restrict__ counter,
    const int* __restrict__ eFlat,
    const float* __restrict__ eAgg,
    const _Float16* __restrict__ w1p,
    const _Float16* __restrict__ w2T,
    const float* __restrict__ b2,
    const _Float16* __restrict__ w3T,
    const float* __restrict__ b3,
    const float* __restrict__ latent,
    float* __restrict__ kv)
{
    __shared__ __align__(16) _Float16 h1pool[64*520];
    __shared__ __align__(16) _Float16 w1s[512*8];
    __shared__ float aggs[64][6];
    __shared__ int   flatS[64];
    _Float16* h2h = h1pool;

    int t = threadIdx.x;
    int E = counter[0]; if (E > ECAP) E = ECAP;
    int s = blockIdx.x * 64;
    if (s >= E) return;
    int ne = min(64, E - s);

    for (int i = t; i < 512; i += 256)
        ((int4*)w1s)[i] = ((const int4*)w1p)[i];
    for (int i = t; i < 384; i += 256)
        aggs[i/6][i - (i/6)*6] = (i < ne*6) ? eAgg[(size_t)s*6 + i] : 0.0f;
    if (t < 64) flatS[t] = (t < ne) ? eFlat[s + t] : 0;
    __syncthreads();

    int e = t & 63;
    int w = t >> 6;
    {
        float a0 = aggs[e][0], a1 = aggs[e][1], a2 = aggs[e][2];
        float a3 = aggs[e][3], a4 = aggs[e][4], a5 = aggs[e][5];
        int xk = (e >> 3) & 7;
        #pragma unroll
        for (int ci = 0; ci < 16; ++ci) {
            int c = w*16 + ci;
            f16x8 v;
            #pragma unroll
            for (int jj = 0; jj < 8; ++jj) {
                int k = c*8 + jj;
                f16x8 wv = *(const f16x8*)&w1s[k*8];
                float pre = (float)wv[6]
                    + a0*(float)wv[0] + a1*(float)wv[1] + a2*(float)wv[2]
                    + a3*(float)wv[3] + a4*(float)wv[4] + a5*(float)wv[5];
                v[jj] = (_Float16)gelu_f(pre);
            }
            *(f16x8*)&h1pool[e*520 + ((c ^ xk)*8)] = v;
        }
    }
    __syncthreads();

    int lane = t & 63;
    int l15 = lane & 15, g = lane >> 4;

    f32x4 acc2[4][4];
    #pragma unroll
    for (int nt = 0; nt < 4; ++nt) {
        float bb = b2[w*64 + nt*16 + l15];
        #pragma unroll
        for (int mt = 0; mt < 4; ++mt) acc2[mt][nt] = (f32x4){bb, bb, bb, bb};
    }
    #pragma unroll 4
    for (int kk = 0; kk < 16; ++kk) {
        f16x8 af[4];
        #pragma unroll
        for (int mt = 0; mt < 4; ++mt) {
            int ee = mt*16 + l15;
            af[mt] = *(const f16x8*)&h1pool[ee*520 + (((kk*4 + g) ^ ((ee>>3)&7))*8)];
        }
        #pragma unroll
        for (int nt = 0; nt < 4; ++nt) {
            f16x8 bf = *(const f16x8*)&w2T[(size_t)(w*64 + nt*16 + l15)*512 + kk*32 + g*8];
            #pragma unroll
            for (int mt = 0; mt < 4; ++mt)
                acc2[mt][nt] = __builtin_amdgcn_mfma_f32_16x16x32_f16(af[mt], bf, acc2[mt][nt], 0, 0, 0);
        }
    }
    __syncthreads();
    #pragma unroll
    for (int mt = 0; mt < 4; ++mt)
      #pragma unroll
      for (int nt = 0; nt < 4; ++nt) {
        int n = w*64 + nt*16 + l15;
        #pragma unroll
        for (int r = 0; r < 4; ++r) {
            int m = mt*16 + g*4 + r;
            h2h[m*264 + (((n>>3) ^ (m&7))*8) + (n&7)] = (_Float16)gelu_f(acc2[mt][nt][r]);
        }
      }
    __syncthreads();

    int o = w*16 + l15;
    f32x4 acc3[4];
    { float bb = b3[o];
      #pragma unroll
      for (int mt = 0; mt < 4; ++mt) acc3[mt] = (f32x4){bb, bb, bb, bb}; }
    #pragma unroll 2
    for (int kk2 = 0; kk2 < 8; ++kk2) {
        f16x8 bf = *(const f16x8*)&w3T[(size_t)o*256 + kk2*32 + g*8];
        #pragma unroll
        for (int mt = 0; mt < 4; ++mt) {
            int ee = mt*16 + l15;
            f16x8 af = *(const f16x8*)&h2h[ee*264 + (((kk2*4 + g) ^ (ee&7))*8)];
            acc3[mt] = __builtin_amdgcn_mfma_f32_16x16x32_f16(af, bf, acc3[mt], 0, 0, 0);
        }
    }

    #pragma unroll
    for (int mt = 0; mt < 4; ++mt) {
        #pragma unroll
        for (int r = 0; r < 4; ++r) {
            int ee = mt*16 + g*4 + r;
            if (ee < ne) {
                float fy = latent[(size_t)flatS[ee]*64 + o];
                kv[(size_t)(s + ee)*64 + o] = acc3[mt][r] * fy;
            }
        }
    }
}

// ---------------- projection + kv gather (unchanged) -----------------------
__global__ __launch_bounds__(256) void k_project(const int* __restrict__ baseG,
                                                 const int* __restrict__ cntG,
                                                 const float* __restrict__ kv,
                                                 const float* __restrict__ pw1,
                                                 const float* __restrict__ pb1,
                                                 const float* __restrict__ pw2,
                                                 const float* __restrict__ pb2,
                                                 float* __restrict__ outp)
{
    __shared__ float w1s[64*260];
    __shared__ float xT[64*68];
    __shared__ float w2s[256];
    __shared__ float b1s[256];
    __shared__ float red[64*4];
    int t = threadIdx.x;
    int p0 = blockIdx.x * 64;
    for (int i = t; i < 16384; i += 256) {
        int k = i >> 8, o = i & 255;
        w1s[k*260 + o] = pw1[i];
    }
    w2s[t] = pw2[t];
    b1s[t] = pb1[t];
    for (int i = t; i < 4096; i += 256) {
        int ptl = i >> 6, c = i & 63;
        int p = p0 + ptl;
        int base = baseG[p], cnt = cntG[p];
        float acc = 0.f;
        for (int j = 0; j < cnt; ++j) acc += kv[(size_t)(base + j)*64 + c];
        xT[c*68 + ptl] = acc / fmaxf((float)cnt, 1.0f);
    }
    __syncthreads();
    int pr = t & 15, oc0 = t >> 4;
    float psum[4] = {0.f, 0.f, 0.f, 0.f};
    for (int it = 0; it < 4; ++it) {
        int oc = it*16 + oc0;
        float a[4][4];
        #pragma unroll
        for (int pp = 0; pp < 4; ++pp)
            #pragma unroll
            for (int q = 0; q < 4; ++q) a[pp][q] = b1s[oc*4 + q];
        for (int i = 0; i < 64; ++i) {
            float4 xv = *(const float4*)&xT[i*68 + pr*4];
            float4 wv = *(const float4*)&w1s[i*260 + oc*4];
            #pragma unroll
            for (int q = 0; q < 4; ++q) {
                float wq = (&wv.x)[q];
                a[0][q] += xv.x*wq; a[1][q] += xv.y*wq;
                a[2][q] += xv.z*wq; a[3][q] += xv.w*wq;
            }
        }
        #pragma unroll
        for (int pp = 0; pp < 4; ++pp) {
            float s = 0.f;
            #pragma unroll
            for (int q = 0; q < 4; ++q) s += gelu_f(a[pp][q]) * w2s[oc*4 + q];
            psum[pp] += s;
        }
    }
    #pragma unroll
    for (int pp = 0; pp < 4; ++pp) {
        psum[pp] += __shfl_xor(psum[pp], 16, 64);
        psum[pp] += __shfl_xor(psum[pp], 32, 64);
    }
    int lane = t & 63, w = t >> 6;
    if (lane < 16) {
        #pragma unroll
        for (int pp = 0; pp < 4; ++pp) red[(lane*4 + pp)*4 + w] = psum[pp];
    }
    __syncthreads();
    if (t < 64)
        outp[p0 + t] = red[t*4+0] + red[t*4+1] + red[t*4+2] + red[t*4+3] + pb2[0];
}

// ---------------------------------------------------------------------------
extern "C" void kernel_launch(void* const* d_in, const int* in_sizes, int n_in,
                              void* d_out, int out_size, void* d_ws, size_t ws_size,
                              hipStream_t stream)
{
    const float* in_p = (const float*)d_in[0];
    const float* outp = (const float*)d_in[1];
    const float* f    = (const float*)d_in[2];
    const float* lw1  = (const float*)d_in[3];
    const float* lb1  = (const float*)d_in[4];
    const float* lw2  = (const float*)d_in[5];
    const float* lb2  = (const float*)d_in[6];
    const float* spw  = (const float*)d_in[7];
    const float* skw  = (const float*)d_in[8];
    const float* skb  = (const float*)d_in[9];
    const float* gw1  = (const float*)d_in[10];
    const float* gb1  = (const float*)d_in[11];
    const float* gw2  = (const float*)d_in[12];
    const float* gb2  = (const float*)d_in[13];
    const float* gw3  = (const float*)d_in[14];
    const float* gb3  = (const float*)d_in[15];
    const float* pw1  = (const float*)d_in[16];
    const float* pb1  = (const float*)d_in[17];
    const float* pw2  = (const float*)d_in[18];
    const float* pb2  = (const float*)d_in[19];

    float* ws   = (float*)d_ws;
    float* buf0 = ws;
    float* buf1 = ws + 2097152;
    float* SC   = ws + 4194304;
    float2* F1 = (float2*)SC;
    float2* Ft = (float2*)(SC + 524288);
    float2* Gt = (float2*)(SC + 786432);
    _Float16* w2T  = (_Float16*)(SC + 1048576);
    _Float16* w3T  = (_Float16*)(SC + 1114112);
    _Float16* w1p  = (_Float16*)(SC + 1122304);
    _Float16* l2hi = (_Float16*)(SC + 1124352);
    _Float16* l2lo = (_Float16*)(SC + 1132544);
    _Float16* skwH = (_Float16*)(SC + 1140736);
    _Float16* skwL = (_Float16*)(SC + 1148928);
    int*   counter = (int*)(SC + 1157120);
    int*   baseG   = (int*)(SC + 1157136);
    int*   cntG    = (int*)(SC + 1173520);
    int*   eFlat   = (int*)(SC + 1189904);
    float* eAgg    = SC + 1320976;
    float* kv      = SC + 2107408;
    float* hsk     = SC + 10496016;

    hipMemsetAsync(counter, 0, sizeof(int), stream);
    k_prep<<<784, 256, 0, stream>>>(gw2, gw3, gw1, gb1, lw2, skw, outp,
                                    w2T, w3T, w1p, l2hi, l2lo, skwH, skwL,
                                    counter, baseG, cntG, eFlat, eAgg);
    k_lift<<<512, 256, 0, stream>>>(f, in_p, lw1, lb1, l2hi, l2lo, lb2, buf0);

    k_fwd_zy<<<256, 256, 0, stream>>>(buf0, F1);
    for (int l = 0; l < 4; ++l) {
        const float* hin = (l & 1) ? buf1 : buf0;
        float* hout = (l & 1) ? buf0 : buf1;
        k_fwd_x<<<256, 256, 0, stream>>>(F1, Ft);
        k_spec_skip<<<512, 256, 0, stream>>>(Ft, spw, hin, skwH, skwL, Gt, hsk, l);
        k_inv_zy<<<512, 256, 0, stream>>>(Gt, hsk, skb, hout, buf0, F1,
                                          l, (l < 3) ? 1 : 0);
    }
    // latent = buf0 (point-major, written by k_inv_zy at l=3)

    k_gno_mlp<<<ECAP/64, 256, 0, stream>>>(counter, eFlat, eAgg,
                                           w1p, w2T, gb2, w3T, gb3, buf0, kv);
    k_project<<<256, 256, 0, stream>>>(baseG, cntG, kv, pw1, pb1, pw2, pb2,
                                       (float*)d_out);
}

// Round 12
// 356.538 us; speedup vs baseline: 1.1761x; 1.0009x over previous
//
#include <hip/hip_runtime.h>
#include <math.h>

// ---------------------------------------------------------------------------
// FNO-GNO round 12: revert to round 10 (cooperative launch failed under graph
// capture in r11 -- kernel silently never ran). r10 = plateau: 356.9us,
// absmax 2.44e-4. Residual ~150us is serial-dispatch boundary cost across 17
// dependency-chained dispatches; the only remaining fusion tool (grid-wide
// sync) is unavailable under graph capture.
// ---------------------------------------------------------------------------

#define ECAP 131072

typedef _Float16 f16x8 __attribute__((ext_vector_type(8)));
typedef float f32x4 __attribute__((ext_vector_type(4)));

__device__ __forceinline__ float gelu_f(float x) {
    float t = fabsf(x) * 0.7071067811865475f;
    float k = __builtin_amdgcn_rcpf(1.0f + 0.3275911f * t);
    float e = __expf(-t * t);
    float y = k*(0.254829592f + k*(-0.284496736f + k*(1.421413741f +
              k*(-1.453152027f + k*1.061405429f))));
    float erfv = 1.0f - y * e;
    return 0.5f * x * (1.0f + copysignf(erfv, x));
}

// ---------------- prep (weights) + GNO edge build, fused --------------------
__global__ __launch_bounds__(256) void k_prep(const float* __restrict__ w2,
                                              const float* __restrict__ w3,
                                              const float* __restrict__ w1,
                                              const float* __restrict__ b1,
                                              const float* __restrict__ lw2,
                                              const float* __restrict__ skw,
                                              const float* __restrict__ out_p,
                                              _Float16* __restrict__ w2T,
                                              _Float16* __restrict__ w3T,
                                              _Float16* __restrict__ w1p,
                                              _Float16* __restrict__ l2hi,
                                              _Float16* __restrict__ l2lo,
                                              _Float16* __restrict__ skwH,
                                              _Float16* __restrict__ skwL,
                                              int* __restrict__ counter,
                                              int* __restrict__ baseG,
                                              int* __restrict__ cntG,
                                              int* __restrict__ eFlat,
                                              float* __restrict__ eAgg)
{
    if (blockIdx.x >= 720) {
        int n = (blockIdx.x - 720)*256 + threadIdx.x;
        const float hg = 1.0f/31.0f;
        const float r2 = (float)(0.033*0.033);
        float px = out_p[n*3+0], py = out_p[n*3+1], pz = out_p[n*3+2];
        int ix = (int)rintf(px*31.f), iy = (int)rintf(py*31.f), iz = (int)rintf(pz*31.f);
        unsigned msk = 0; int cnt = 0;
        for (int j = 0; j < 27; ++j) {
            int dx = j/9 - 1, dy = (j/3)%3 - 1, dz = j%3 - 1;
            int cx = ix+dx, cy = iy+dy, cz = iz+dz;
            bool inb = (cx>=0)&&(cx<32)&&(cy>=0)&&(cy<32)&&(cz>=0)&&(cz<32);
            int qx = min(max(cx,0),31), qy = min(max(cy,0),31), qz = min(max(cz,0),31);
            float yx = qx*hg, yy = qy*hg, yz = qz*hg;
            float d2 = (px-yx)*(px-yx) + (py-yy)*(py-yy) + (pz-yz)*(pz-yz);
            if (inb && d2 <= r2) { msk |= 1u<<j; cnt++; }
        }
        int base = atomicAdd(counter, cnt);
        baseG[n] = base; cntG[n] = cnt;
        int k = 0;
        for (int j = 0; j < 27; ++j) if (msk & (1u<<j)) {
            int dx = j/9 - 1, dy = (j/3)%3 - 1, dz = j%3 - 1;
            int cx = ix+dx, cy = iy+dy, cz = iz+dz;
            int e = base + k;
            eFlat[e] = (cx*32 + cy)*32 + cz;
            eAgg[e*6+0] = cx*hg; eAgg[e*6+1] = cy*hg; eAgg[e*6+2] = cz*hg;
            eAgg[e*6+3] = px;    eAgg[e*6+4] = py;    eAgg[e*6+5] = pz;
            ++k;
        }
        return;
    }
    int idx = blockIdx.x*256 + threadIdx.x;
    if (idx < 131072) {
        int k = idx >> 8, n = idx & 255;
        w2T[n*512 + k] = (_Float16)w2[idx];
    } else if (idx < 147456) {
        int j = idx - 131072;
        int k = j >> 6, o = j & 63;
        w3T[o*256 + k] = (_Float16)w3[j];
    } else if (idx < 151552) {
        int j = idx - 147456;
        int k = j >> 3, d = j & 7;
        float v = d < 6 ? w1[d*512 + k] : (d == 6 ? b1[k] : 0.0f);
        w1p[k*8 + d] = (_Float16)v;
    } else if (idx < 167936) {
        int j = idx - 151552;
        int o = j >> 8, k = j & 255;
        float v = lw2[k*64 + o];
        _Float16 hi = (_Float16)v;
        l2hi[j] = hi;
        l2lo[j] = (_Float16)(v - (float)hi);
    } else if (idx < 184320) {
        int j = idx - 167936;
        int l = j >> 12, r = j & 4095;
        int co = r >> 6, ci = r & 63;
        float v = skw[l*4096 + ci*64 + co];
        _Float16 hi = (_Float16)v;
        skwH[j] = hi;
        skwL[j] = (_Float16)(v - (float)hi);
    }
}

// ---------------- lifting via split-fp16 MFMA ------------------------------
__global__ __launch_bounds__(256) void k_lift(
    const float* __restrict__ f, const float* __restrict__ in_p,
    const float* __restrict__ w1, const float* __restrict__ b1,
    const _Float16* __restrict__ l2hi,
    const _Float16* __restrict__ l2lo,
    const float* __restrict__ b2,
    float* __restrict__ h)
{
    __shared__ __align__(16) _Float16 h1hi[64*264];
    __shared__ __align__(16) _Float16 h1lo[64*264];
    __shared__ float w1s[6*256];
    __shared__ float b1s[256];
    float* oT = (float*)h1hi;
    int t = threadIdx.x;
    for (int i = t; i < 1536; i += 256) w1s[i] = w1[i];
    b1s[t] = b1[t];
    int p0 = blockIdx.x * 64;
    int pt = t >> 2, jq = t & 3;
    int p = p0 + pt;
    float x0 = f[p*3+0], x1 = f[p*3+1], x2 = f[p*3+2];
    float x3 = in_p[p*3+0], x4 = in_p[p*3+1], x5 = in_p[p*3+2];
    __syncthreads();
    for (int r = 0; r < 8; ++r) {
        int j0 = jq*64 + r*8;
        f16x8 vh, vl;
        #pragma unroll
        for (int jj = 0; jj < 8; ++jj) {
            int j = j0 + jj;
            float a = b1s[j] + x0*w1s[j] + x1*w1s[256+j] + x2*w1s[512+j]
                    + x3*w1s[768+j] + x4*w1s[1024+j] + x5*w1s[1280+j];
            float g = gelu_f(a);
            _Float16 hi = (_Float16)g;
            vh[jj] = hi;
            vl[jj] = (_Float16)(g - (float)hi);
        }
        *(f16x8*)&h1hi[pt*264 + j0] = vh;
        *(f16x8*)&h1lo[pt*264 + j0] = vl;
    }
    __syncthreads();
    int w = t >> 6, lane = t & 63, l15 = lane & 15, g = lane >> 4;
    f32x4 acc[4];
    #pragma unroll
    for (int nt = 0; nt < 4; ++nt) {
        float bb = b2[nt*16 + l15];
        acc[nt] = (f32x4){bb, bb, bb, bb};
    }
    for (int kk = 0; kk < 8; ++kk) {
        f16x8 ah = *(const f16x8*)&h1hi[(w*16+l15)*264 + kk*32 + g*8];
        f16x8 al = *(const f16x8*)&h1lo[(w*16+l15)*264 + kk*32 + g*8];
        #pragma unroll
        for (int nt = 0; nt < 4; ++nt) {
            f16x8 bh = *(const f16x8*)&l2hi[(nt*16+l15)*256 + kk*32 + g*8];
            f16x8 bl = *(const f16x8*)&l2lo[(nt*16+l15)*256 + kk*32 + g*8];
            acc[nt] = __builtin_amdgcn_mfma_f32_16x16x32_f16(al, bh, acc[nt], 0, 0, 0);
            acc[nt] = __builtin_amdgcn_mfma_f32_16x16x32_f16(ah, bl, acc[nt], 0, 0, 0);
            acc[nt] = __builtin_amdgcn_mfma_f32_16x16x32_f16(ah, bh, acc[nt], 0, 0, 0);
        }
    }
    __syncthreads();
    #pragma unroll
    for (int nt = 0; nt < 4; ++nt)
        #pragma unroll
        for (int r = 0; r < 4; ++r)
            oT[(nt*16 + l15)*68 + w*16 + g*4 + r] = acc[nt][r];
    __syncthreads();
    for (int i = t; i < 4096; i += 256) {
        int c = i >> 6, ptl = i & 63;
        h[(size_t)c*32768 + p0 + ptl] = oT[c*68 + ptl];
    }
}

// ---------------- kA: fused z+y forward DFT (layer 0 only) -----------------
__global__ __launch_bounds__(256) void k_fwd_zy(const float* __restrict__ h,
                                                float2* __restrict__ F1)
{
    __shared__ float pl[8*1056];
    __shared__ float2 fz[32*73];
    __shared__ float twc[32], tws[32];
    int t = threadIdx.x;
    int x = blockIdx.x >> 3, cg = blockIdx.x & 7;
    for (int i = t; i < 8192; i += 256) {
        int c = i >> 10, yz = i & 1023;
        pl[c*1056 + (yz>>5)*33 + (yz&31)] = h[(cg*8 + c)*32768 + x*1024 + yz];
    }
    if (t < 32) { float th = (float)t*(6.283185307179586f/32.f); twc[t]=cosf(th); tws[t]=sinf(th); }
    __syncthreads();
    {
        int c = t >> 5, y = t & 31;
        float zv[32];
        #pragma unroll
        for (int z = 0; z < 32; ++z) zv[z] = pl[c*1056 + y*33 + z];
        const float inv = 1.0f/32768.0f;
        #pragma unroll
        for (int kz = 0; kz < 8; ++kz) {
            float re = 0.f, im = 0.f;
            #pragma unroll
            for (int z = 0; z < 32; ++z) {
                int ph = (kz*z)&31;
                re += zv[z]*twc[ph];
                im -= zv[z]*tws[ph];
            }
            fz[y*73 + kz*9 + c] = make_float2(re*inv, im*inv);
        }
    }
    __syncthreads();
    #pragma unroll
    for (int ko = 0; ko < 4; ++ko) {
        int idx = ko*256 + t;
        int kyi = idx >> 6, kz = (idx >> 3) & 7, c = idx & 7;
        int ky = kyi < 8 ? kyi : kyi + 16;
        float re = 0.f, im = 0.f;
        for (int y = 0; y < 32; ++y) {
            int ph = (ky*y)&31;
            float cc = twc[ph], ss = tws[ph];
            float2 a = fz[y*73 + kz*9 + c];
            re += a.x*cc + a.y*ss;
            im += a.y*cc - a.x*ss;
        }
        F1[((kyi*8 + kz)*32 + x)*64 + cg*8 + c] = make_float2(re, im);
    }
}

// ---------------- kAx: x forward DFT, 256 blocks ---------------------------
__global__ __launch_bounds__(256) void k_fwd_x(const float2* __restrict__ F1,
                                               float2* __restrict__ Ft)
{
    __shared__ float2 fs[32*33];
    __shared__ float twc[32], tws[32];
    int t = threadIdx.x;
    int b = blockIdx.x;
    int kyi = b >> 4, kz = (b >> 1) & 7, ih = b & 1;
    const float2* src = &F1[(size_t)((kyi*8 + kz)*32)*64 + ih*32];
    for (int i = t; i < 1024; i += 256) {
        int xx = i >> 5, il = i & 31;
        fs[xx*33 + il] = src[xx*64 + il];
    }
    if (t < 32) { float th = (float)t*(6.283185307179586f/32.f); twc[t]=cosf(th); tws[t]=sinf(th); }
    __syncthreads();
    #pragma unroll
    for (int ko = 0; ko < 2; ++ko) {
        int idx = ko*256 + t;
        int kxi = idx >> 5, il = idx & 31;
        int kx = kxi < 8 ? kxi : kxi + 16;
        float re = 0.f, im = 0.f;
        for (int xx = 0; xx < 32; ++xx) {
            int ph = (kx*xx)&31;
            float cc = twc[ph], ss = tws[ph];
            float2 a = fs[xx*33 + il];
            re += a.x*cc + a.y*ss;
            im += a.y*cc - a.x*ss;
        }
        Ft[((kxi*16 + kyi)*8 + kz)*64 + ih*32 + il] = make_float2(re, im);
    }
}

// ---------------- kB: spectral (0-255) + skip GEMM (256-511), LDS overlay --
__global__ __launch_bounds__(256) void k_spec_skip(const float2* __restrict__ Ft,
                                                   const float* __restrict__ spw,
                                                   const float* __restrict__ hold,
                                                   const _Float16* __restrict__ skwH,
                                                   const _Float16* __restrict__ skwL,
                                                   float2* __restrict__ Gt,
                                                   float* __restrict__ hsk,
                                                   int l)
{
    __shared__ __align__(16) char pool[36864];
    int t = threadIdx.x;
    if (blockIdx.x >= 256) {
        _Float16* shi = (_Float16*)pool;              // 128*72 halves
        _Float16* slo = (_Float16*)(pool + 18432);
        int pt0 = (blockIdx.x - 256) * 128;
        for (int i = t; i < 2048; i += 256) {
            int ci = i >> 5, q = i & 31;
            float4 v = *(const float4*)&hold[(size_t)ci*32768 + pt0 + q*4];
            #pragma unroll
            for (int j = 0; j < 4; ++j) {
                float fv = (&v.x)[j];
                _Float16 hi = (_Float16)fv;
                shi[(q*4+j)*72 + ci] = hi;
                slo[(q*4+j)*72 + ci] = (_Float16)(fv - (float)hi);
            }
        }
        __syncthreads();
        int w = t >> 6, lane = t & 63, l15 = lane & 15, g = lane >> 4;
        f32x4 acc[8];
        #pragma unroll
        for (int nt = 0; nt < 8; ++nt) acc[nt] = (f32x4){0.f, 0.f, 0.f, 0.f};
        #pragma unroll
        for (int kk = 0; kk < 2; ++kk) {
            f16x8 ah = *(const f16x8*)&skwH[l*4096 + (w*16+l15)*64 + kk*32 + g*8];
            f16x8 al = *(const f16x8*)&skwL[l*4096 + (w*16+l15)*64 + kk*32 + g*8];
            #pragma unroll
            for (int nt = 0; nt < 8; ++nt) {
                f16x8 bh = *(const f16x8*)&shi[(nt*16+l15)*72 + kk*32 + g*8];
                f16x8 bl = *(const f16x8*)&slo[(nt*16+l15)*72 + kk*32 + g*8];
                acc[nt] = __builtin_amdgcn_mfma_f32_16x16x32_f16(al, bh, acc[nt], 0, 0, 0);
                acc[nt] = __builtin_amdgcn_mfma_f32_16x16x32_f16(ah, bl, acc[nt], 0, 0, 0);
                acc[nt] = __builtin_amdgcn_mfma_f32_16x16x32_f16(ah, bh, acc[nt], 0, 0, 0);
            }
        }
        #pragma unroll
        for (int nt = 0; nt < 8; ++nt)
            #pragma unroll
            for (int r = 0; r < 4; ++r)
                hsk[(size_t)(w*16 + g*4 + r)*32768 + pt0 + nt*16 + l15] = acc[nt][r];
        return;
    }
    float2* ft2 = (float2*)pool;                      // 64*65 float2 = 33280 B
    int og8 = blockIdx.x >> 5, corner = (blockIdx.x >> 3) & 3, mx = blockIdx.x & 7;
    int kxi = mx + (corner >> 1)*8;
    int kyB = (corner & 1)*8;
    {
        int m = t >> 2, iq = t & 3;
        int my = m >> 3, mz = m & 7;
        int rho = (m >> 1) + ((m & 1) << 5);
        const float2* src = &Ft[(size_t)((kxi*16 + kyB + my)*8 + mz)*64];
        #pragma unroll
        for (int ii = 0; ii < 16; ++ii) {
            int i = iq*16 + ii;
            ft2[rho*65 + i] = src[i];
        }
    }
    __syncthreads();
    int mp = t & 31, oq = t >> 5;
    int o = og8*8 + oq;
    int m0 = 2*mp;
    size_t wbase = (size_t)(l*4 + corner)*4194304 + (size_t)o*1024
                 + (size_t)mx*128 + m0*2;
    float ar0 = 0.f, ai0 = 0.f, ar1 = 0.f, ai1 = 0.f;
    for (int i8 = 0; i8 < 64; i8 += 8) {
        float4 wv[8];
        #pragma unroll
        for (int u = 0; u < 8; ++u)
            wv[u] = *(const float4*)&spw[wbase + (size_t)(i8+u)*65536];
        #pragma unroll
        for (int u = 0; u < 8; ++u) {
            float2 f0 = ft2[mp*65 + i8 + u];
            float2 f1 = ft2[(32 + mp)*65 + i8 + u];
            ar0 += f0.x*wv[u].x - f0.y*wv[u].y;
            ai0 += f0.x*wv[u].y + f0.y*wv[u].x;
            ar1 += f1.x*wv[u].z - f1.y*wv[u].w;
            ai1 += f1.x*wv[u].w + f1.y*wv[u].z;
        }
    }
    size_t gbase = (size_t)(o >> 2)*8192 + (size_t)(corner*8 + mx)*256 + (o & 3);
    Gt[gbase + (size_t)m0*4]       = make_float2(ar0, ai0);
    Gt[gbase + (size_t)(m0+1)*4]   = make_float2(ar1, ai1);
}

// ---------------- kC: inv-x/y/z + skip-add + gelu + next-layer z+y DFT -----
// grid 512 = (x 32) x (cg4 16); 256 threads; ~29 KB LDS => 2+ blocks/CU.
__global__ __launch_bounds__(256) void k_inv_zy(const float2* __restrict__ Gt,
                                                const float* __restrict__ hsk,
                                                const float* __restrict__ skb,
                                                float* __restrict__ hnew,
                                                float* __restrict__ latent,
                                                float2* __restrict__ F1,
                                                int l, int do_zy)
{
    __shared__ __align__(16) char pool[29568];
    __shared__ float twc[32], tws[32];
    float2* s1 = (float2*)pool;                  // [kyi16][kz8][o4]       4096 B
    float2* s2 = (float2*)(pool + 4096);         // [y32][33-pad rows]     8448 B
    float*  pl = (float*)(pool + 12544);         // [c4][y32][z33]        16896 B
    float2* fz = (float2*)pool;                  // [y32][33] aliases s1/s2 (8448 B)

    int t = threadIdx.x;
    int x = blockIdx.x >> 4, cg = blockIdx.x & 15;
    if (t < 32) { float th = (float)t*(6.283185307179586f/32.f); twc[t]=cosf(th); tws[t]=sinf(th); }
    __syncthreads();
    // phase A: inv-x (direct Gt reads from L2)
    #pragma unroll
    for (int ko = 0; ko < 2; ++ko) {
        int idx = ko*256 + t;                    // (kyi*8+kz)*4 + o
        int kyi = idx >> 5, kz = (idx >> 2) & 7, o = idx & 3;
        int cy = kyi >> 3, my = kyi & 7;
        const float2* gb = Gt + (size_t)cg*8192 + my*32 + kz*4 + o;
        float re = 0.f, im = 0.f;
        #pragma unroll
        for (int cxh = 0; cxh < 2; ++cxh) {
            int corner = cxh*2 + cy;
            #pragma unroll
            for (int mxx = 0; mxx < 8; ++mxx) {
                int kxi = cxh*8 + mxx;
                int kx = kxi < 8 ? kxi : kxi + 16;
                int ph = (kx * x) & 31;
                float cc = twc[ph], ss = tws[ph];
                float2 a = gb[(corner*8 + mxx)*256];
                re += a.x*cc - a.y*ss;
                im += a.x*ss + a.y*cc;
            }
        }
        s1[idx] = make_float2(re, im);
    }
    __syncthreads();
    // phase B: inv-y (s2 rows padded: stride 33)
    #pragma unroll
    for (int ko = 0; ko < 4; ++ko) {
        int idx = ko*256 + t;                    // (y*8+kz)*4 + o
        int y = idx >> 5, rem = idx & 31;        // rem = kz*4+o
        int kz = rem >> 2, o = rem & 3;
        float re = 0.f, im = 0.f;
        #pragma unroll
        for (int kyi = 0; kyi < 16; ++kyi) {
            int ky = kyi < 8 ? kyi : kyi + 16;
            int ph = (ky*y) & 31;
            float cc = twc[ph], ss = tws[ph];
            float2 a = s1[kyi*32 + kz*4 + o];
            re += a.x*cc - a.y*ss;
            im += a.x*ss + a.y*cc;
        }
        s2[y*33 + rem] = make_float2(re, im);
    }
    __syncthreads();
    // phase C: inv-z + skip-add + gelu; thread owns 4 points x 4 channels
    {
        float outv[4][4];
        #pragma unroll
        for (int o = 0; o < 4; ++o) {
            float bb = skb[l*64 + cg*4 + o];
            float4 hv = *(const float4*)&hsk[(size_t)(cg*4+o)*32768 + x*1024 + t*4];
            outv[0][o] = bb + hv.x; outv[1][o] = bb + hv.y;
            outv[2][o] = bb + hv.z; outv[3][o] = bb + hv.w;
        }
        #pragma unroll
        for (int pp = 0; pp < 4; ++pp) {
            int pt = t*4 + pp;
            int y = pt >> 5, z = pt & 31;
            #pragma unroll
            for (int o = 0; o < 4; ++o) {
                float s = s2[y*33 + o].x;        // kz=0 (imag discarded)
                #pragma unroll
                for (int kz = 1; kz < 8; ++kz) {
                    int ph = (kz*z) & 31;
                    float2 a = s2[y*33 + kz*4 + o];
                    s += 2.0f*(a.x*twc[ph] - a.y*tws[ph]);
                }
                float v = s + outv[pp][o];
                outv[pp][o] = (l < 3) ? gelu_f(v) : v;
            }
        }
        if (l < 3) {
            int pt = t*4;
            int y = pt >> 5, z = pt & 31;       // 4 consecutive z, same y
            #pragma unroll
            for (int o = 0; o < 4; ++o) {
                pl[o*1056 + y*33 + z + 0] = outv[0][o];
                pl[o*1056 + y*33 + z + 1] = outv[1][o];
                pl[o*1056 + y*33 + z + 2] = outv[2][o];
                pl[o*1056 + y*33 + z + 3] = outv[3][o];
                *(float4*)&hnew[(size_t)(cg*4+o)*32768 + x*1024 + pt] =
                    make_float4(outv[0][o], outv[1][o], outv[2][o], outv[3][o]);
            }
        } else {
            #pragma unroll
            for (int pp = 0; pp < 4; ++pp) {
                int pt = t*4 + pp;
                *(float4*)&latent[(size_t)(x*1024 + pt)*64 + cg*4] =
                    make_float4(outv[pp][0], outv[pp][1], outv[pp][2], outv[pp][3]);
            }
        }
    }
    if (!do_zy) return;
    __syncthreads();
    // fused next-layer z-stage: thread (c = t>>6, y = (t>>1)&31, sub = t&1)
    {
        int c = t >> 6, y = (t >> 1) & 31, sub = t & 1;
        float zv[32];
        #pragma unroll
        for (int z = 0; z < 32; ++z) zv[z] = pl[c*1056 + y*33 + z];
        const float inv = 1.0f/32768.0f;
        #pragma unroll
        for (int kq = 0; kq < 4; ++kq) {
            int kz = sub*4 + kq;
            float re = 0.f, im = 0.f;
            #pragma unroll
            for (int z = 0; z < 32; ++z) {
                int ph = (kz*z)&31;
                re += zv[z]*twc[ph];
                im -= zv[z]*tws[ph];
            }
            fz[y*33 + kz*4 + c] = make_float2(re*inv, im*inv);
        }
    }
    __syncthreads();
    // fused next-layer y-stage -> F1
    #pragma unroll
    for (int ko = 0; ko < 2; ++ko) {
        int idx = ko*256 + t;                    // kyi*32 + kz*4 + c
        int kyi = idx >> 5, rem = idx & 31;
        int kz = rem >> 2, c = rem & 3;
        int ky = kyi < 8 ? kyi : kyi + 16;
        float re = 0.f, im = 0.f;
        for (int y = 0; y < 32; ++y) {
            int ph = (ky*y)&31;
            float cc = twc[ph], ss = tws[ph];
            float2 a = fz[y*33 + kz*4 + c];
            re += a.x*cc + a.y*ss;
            im += a.y*cc - a.x*ss;
        }
        F1[((kyi*8 + kz)*32 + x)*64 + cg*4 + c] = make_float2(re, im);
    }
}

// ---------------- GNO stage 2: dense 64-edge MLP tiles ---------------------
__global__ __launch_bounds__(256, 2) void k_gno_mlp(
    const int* __restrict__ counter,
    const int* __restrict__ eFlat,
    const float* __restrict__ eAgg,
    const _Float16* __restrict__ w1p,
    const _Float16* __restrict__ w2T,
    const float* __restrict__ b2,
    const _Float16* __restrict__ w3T,
    const float* __restrict__ b3,
    const float* __restrict__ latent,
    float* __restrict__ kv)
{
    __shared__ __align__(16) _Float16 h1pool[64*520];
    __shared__ __align__(16) _Float16 w1s[512*8];
    __shared__ float aggs[64][6];
    __shared__ int   flatS[64];
    _Float16* h2h = h1pool;

    int t = threadIdx.x;
    int E = counter[0]; if (E > ECAP) E = ECAP;
    int s = blockIdx.x * 64;
    if (s >= E) return;
    int ne = min(64, E - s);

    for (int i = t; i < 512; i += 256)
        ((int4*)w1s)[i] = ((const int4*)w1p)[i];
    for (int i = t; i < 384; i += 256)
        aggs[i/6][i - (i/6)*6] = (i < ne*6) ? eAgg[(size_t)s*6 + i] : 0.0f;
    if (t < 64) flatS[t] = (t < ne) ? eFlat[s + t] : 0;
    __syncthreads();

    int e = t & 63;
    int w = t >> 6;
    {
        float a0 = aggs[e][0], a1 = aggs[e][1], a2 = aggs[e][2];
        float a3 = aggs[e][3], a4 = aggs[e][4], a5 = aggs[e][5];
        int xk = (e >> 3) & 7;
        #pragma unroll
        for (int ci = 0; ci < 16; ++ci) {
            int c = w*16 + ci;
            f16x8 v;
            #pragma unroll
            for (int jj = 0; jj < 8; ++jj) {
                int k = c*8 + jj;
                f16x8 wv = *(const f16x8*)&w1s[k*8];
                float pre = (float)wv[6]
                    + a0*(float)wv[0] + a1*(float)wv[1] + a2*(float)wv[2]
                    + a3*(float)wv[3] + a4*(float)wv[4] + a5*(float)wv[5];
                v[jj] = (_Float16)gelu_f(pre);
            }
            *(f16x8*)&h1pool[e*520 + ((c ^ xk)*8)] = v;
        }
    }
    __syncthreads();

    int lane = t & 63;
    int l15 = lane & 15, g = lane >> 4;

    f32x4 acc2[4][4];
    #pragma unroll
    for (int nt = 0; nt < 4; ++nt) {
        float bb = b2[w*64 + nt*16 + l15];
        #pragma unroll
        for (int mt = 0; mt < 4; ++mt) acc2[mt][nt] = (f32x4){bb, bb, bb, bb};
    }
    #pragma unroll 4
    for (int kk = 0; kk < 16; ++kk) {
        f16x8 af[4];
        #pragma unroll
        for (int mt = 0; mt < 4; ++mt) {
            int ee = mt*16 + l15;
            af[mt] = *(const f16x8*)&h1pool[ee*520 + (((kk*4 + g) ^ ((ee>>3)&7))*8)];
        }
        #pragma unroll
        for (int nt = 0; nt < 4; ++nt) {
            f16x8 bf = *(const f16x8*)&w2T[(size_t)(w*64 + nt*16 + l15)*512 + kk*32 + g*8];
            #pragma unroll
            for (int mt = 0; mt < 4; ++mt)
                acc2[mt][nt] = __builtin_amdgcn_mfma_f32_16x16x32_f16(af[mt], bf, acc2[mt][nt], 0, 0, 0);
        }
    }
    __syncthreads();
    #pragma unroll
    for (int mt = 0; mt < 4; ++mt)
      #pragma unroll
      for (int nt = 0; nt < 4; ++nt) {
        int n = w*64 + nt*16 + l15;
        #pragma unroll
        for (int r = 0; r < 4; ++r) {
            int m = mt*16 + g*4 + r;
            h2h[m*264 + (((n>>3) ^ (m&7))*8) + (n&7)] = (_Float16)gelu_f(acc2[mt][nt][r]);
        }
      }
    __syncthreads();

    int o = w*16 + l15;
    f32x4 acc3[4];
    { float bb = b3[o];
      #pragma unroll
      for (int mt = 0; mt < 4; ++mt) acc3[mt] = (f32x4){bb, bb, bb, bb}; }
    #pragma unroll 2
    for (int kk2 = 0; kk2 < 8; ++kk2) {
        f16x8 bf = *(const f16x8*)&w3T[(size_t)o*256 + kk2*32 + g*8];
        #pragma unroll
        for (int mt = 0; mt < 4; ++mt) {
            int ee = mt*16 + l15;
            f16x8 af = *(const f16x8*)&h2h[ee*264 + (((kk2*4 + g) ^ (ee&7))*8)];
            acc3[mt] = __builtin_amdgcn_mfma_f32_16x16x32_f16(af, bf, acc3[mt], 0, 0, 0);
        }
    }

    #pragma unroll
    for (int mt = 0; mt < 4; ++mt) {
        #pragma unroll
        for (int r = 0; r < 4; ++r) {
            int ee = mt*16 + g*4 + r;
            if (ee < ne) {
                float fy = latent[(size_t)flatS[ee]*64 + o];
                kv[(size_t)(s + ee)*64 + o] = acc3[mt][r] * fy;
            }
        }
    }
}

// ---------------- projection + kv gather -----------------------------------
__global__ __launch_bounds__(256) void k_project(const int* __restrict__ baseG,
                                                 const int* __restrict__ cntG,
                                                 const float* __restrict__ kv,
                                                 const float* __restrict__ pw1,
                                                 const float* __restrict__ pb1,
                                                 const float* __restrict__ pw2,
                                                 const float* __restrict__ pb2,
                                                 float* __restrict__ outp)
{
    __shared__ float w1s[64*260];
    __shared__ float xT[64*68];
    __shared__ float w2s[256];
    __shared__ float b1s[256];
    __shared__ float red[64*4];
    int t = threadIdx.x;
    int p0 = blockIdx.x * 64;
    for (int i = t; i < 16384; i += 256) {
        int k = i >> 8, o = i & 255;
        w1s[k*260 + o] = pw1[i];
    }
    w2s[t] = pw2[t];
    b1s[t] = pb1[t];
    for (int i = t; i < 4096; i += 256) {
        int ptl = i >> 6, c = i & 63;
        int p = p0 + ptl;
        int base = baseG[p], cnt = cntG[p];
        float acc = 0.f;
        for (int j = 0; j < cnt; ++j) acc += kv[(size_t)(base + j)*64 + c];
        xT[c*68 + ptl] = acc / fmaxf((float)cnt, 1.0f);
    }
    __syncthreads();
    int pr = t & 15, oc0 = t >> 4;
    float psum[4] = {0.f, 0.f, 0.f, 0.f};
    for (int it = 0; it < 4; ++it) {
        int oc = it*16 + oc0;
        float a[4][4];
        #pragma unroll
        for (int pp = 0; pp < 4; ++pp)
            #pragma unroll
            for (int q = 0; q < 4; ++q) a[pp][q] = b1s[oc*4 + q];
        for (int i = 0; i < 64; ++i) {
            float4 xv = *(const float4*)&xT[i*68 + pr*4];
            float4 wv = *(const float4*)&w1s[i*260 + oc*4];
            #pragma unroll
            for (int q = 0; q < 4; ++q) {
                float wq = (&wv.x)[q];
                a[0][q] += xv.x*wq; a[1][q] += xv.y*wq;
                a[2][q] += xv.z*wq; a[3][q] += xv.w*wq;
            }
        }
        #pragma unroll
        for (int pp = 0; pp < 4; ++pp) {
            float s = 0.f;
            #pragma unroll
            for (int q = 0; q < 4; ++q) s += gelu_f(a[pp][q]) * w2s[oc*4 + q];
            psum[pp] += s;
        }
    }
    #pragma unroll
    for (int pp = 0; pp < 4; ++pp) {
        psum[pp] += __shfl_xor(psum[pp], 16, 64);
        psum[pp] += __shfl_xor(psum[pp], 32, 64);
    }
    int lane = t & 63, w = t >> 6;
    if (lane < 16) {
        #pragma unroll
        for (int pp = 0; pp < 4; ++pp) red[(lane*4 + pp)*4 + w] = psum[pp];
    }
    __syncthreads();
    if (t < 64)
        outp[p0 + t] = red[t*4+0] + red[t*4+1] + red[t*4+2] + red[t*4+3] + pb2[0];
}

// ---------------------------------------------------------------------------
extern "C" void kernel_launch(void* const* d_in, const int* in_sizes, int n_in,
                              void* d_out, int out_size, void* d_ws, size_t ws_size,
                              hipStream_t stream)
{
    const float* in_p = (const float*)d_in[0];
    const float* outp = (const float*)d_in[1];
    const float* f    = (const float*)d_in[2];
    const float* lw1  = (const float*)d_in[3];
    const float* lb1  = (const float*)d_in[4];
    const float* lw2  = (const float*)d_in[5];
    const float* lb2  = (const float*)d_in[6];
    const float* spw  = (const float*)d_in[7];
    const float* skw  = (const float*)d_in[8];
    const float* skb  = (const float*)d_in[9];
    const float* gw1  = (const float*)d_in[10];
    const float* gb1  = (const float*)d_in[11];
    const float* gw2  = (const float*)d_in[12];
    const float* gb2  = (const float*)d_in[13];
    const float* gw3  = (const float*)d_in[14];
    const float* gb3  = (const float*)d_in[15];
    const float* pw1  = (const float*)d_in[16];
    const float* pb1  = (const float*)d_in[17];
    const float* pw2  = (const float*)d_in[18];
    const float* pb2  = (const float*)d_in[19];

    float* ws   = (float*)d_ws;
    float* buf0 = ws;
    float* buf1 = ws + 2097152;
    float* SC   = ws + 4194304;
    float2* F1 = (float2*)SC;
    float2* Ft = (float2*)(SC + 524288);
    float2* Gt = (float2*)(SC + 786432);
    _Float16* w2T  = (_Float16*)(SC + 1048576);
    _Float16* w3T  = (_Float16*)(SC + 1114112);
    _Float16* w1p  = (_Float16*)(SC + 1122304);
    _Float16* l2hi = (_Float16*)(SC + 1124352);
    _Float16* l2lo = (_Float16*)(SC + 1132544);
    _Float16* skwH = (_Float16*)(SC + 1140736);
    _Float16* skwL = (_Float16*)(SC + 1148928);
    int*   counter = (int*)(SC + 1157120);
    int*   baseG   = (int*)(SC + 1157136);
    int*   cntG    = (int*)(SC + 1173520);
    int*   eFlat   = (int*)(SC + 1189904);
    float* eAgg    = SC + 1320976;
    float* kv      = SC + 2107408;
    float* hsk     = SC + 10496016;

    hipMemsetAsync(counter, 0, sizeof(int), stream);
    k_prep<<<784, 256, 0, stream>>>(gw2, gw3, gw1, gb1, lw2, skw, outp,
                                    w2T, w3T, w1p, l2hi, l2lo, skwH, skwL,
                                    counter, baseG, cntG, eFlat, eAgg);
    k_lift<<<512, 256, 0, stream>>>(f, in_p, lw1, lb1, l2hi, l2lo, lb2, buf0);

    k_fwd_zy<<<256, 256, 0, stream>>>(buf0, F1);
    for (int l = 0; l < 4; ++l) {
        const float* hin = (l & 1) ? buf1 : buf0;
        float* hout = (l & 1) ? buf0 : buf1;
        k_fwd_x<<<256, 256, 0, stream>>>(F1, Ft);
        k_spec_skip<<<512, 256, 0, stream>>>(Ft, spw, hin, skwH, skwL, Gt, hsk, l);
        k_inv_zy<<<512, 256, 0, stream>>>(Gt, hsk, skb, hout, buf0, F1,
                                          l, (l < 3) ? 1 : 0);
    }
    // latent = buf0 (point-major, written by k_inv_zy at l=3)

    k_gno_mlp<<<ECAP/64, 256, 0, stream>>>(counter, eFlat, eAgg,
                                           w1p, w2T, gb2, w3T, gb3, buf0, kv);
    k_project<<<256, 256, 0, stream>>>(baseG, cntG, kv, pw1, pb1, pw2, pb2,
                                       (float*)d_out);
}